// Round 1
// baseline (1387.797 us; speedup 1.0000x reference)
//
#include <hip/hip_runtime.h>
#include <hip/hip_bf16.h>
#include <math.h>

static constexpr int NG   = 64;   // graphs
static constexpr int DIN  = 128;
static constexpr int DHID = 128;
static constexpr int DOUT = 64;

// ---------------- small utility kernels ----------------

__global__ void k_zero(float* __restrict__ p, int n) {
  int i = blockIdx.x * blockDim.x + threadIdx.x;
  if (i < n) p[i] = 0.0f;
}

__global__ void k_deg(const int* __restrict__ dst, float* __restrict__ deg, int E) {
  int i = blockIdx.x * blockDim.x + threadIdx.x;
  if (i < E) atomicAdd(&deg[dst[i]], 1.0f);
}

__global__ void k_cnt(const int* __restrict__ batch, float* __restrict__ cnt, int N) {
  int i = blockIdx.x * blockDim.x + threadIdx.x;
  if (i < N) atomicAdd(&cnt[batch[i]], 1.0f);
}

__global__ void k_dinv(const float* __restrict__ deg, float* __restrict__ dinv, int N) {
  int i = blockIdx.x * blockDim.x + threadIdx.x;
  if (i < N) dinv[i] = rsqrtf(deg[i] + 1.0f);  // +1 self-loop; deg>=0 so max(.,1) redundant
}

// ---------------- tiled fp32 GEMM, C = A[M,K] @ B[K,Nc] ----------------
// FUSE_IN:   A element -> relu(a + bias_in[k])   (layer-2 input activation)
// FUSE_SELF: also write Cself[r][c] = dinv[r]^2 * acc  (self-loop message init)
template<bool FUSE_IN, bool FUSE_SELF>
__launch_bounds__(256)
__global__ void sgemm_k(const float* __restrict__ A, const float* __restrict__ B,
                        float* __restrict__ C, float* __restrict__ Cself,
                        const float* __restrict__ bias_in, const float* __restrict__ dinv,
                        int M, int Nc, int K) {
  constexpr int BM = 64, BN = 64, BK = 16, TM = 4, TN = 4;
  __shared__ float As[BK][BM];
  __shared__ float Bs[BK][BN];
  const int bm = blockIdx.x * BM;
  const int bn = blockIdx.y * BN;
  const int tid = threadIdx.x;            // 256 threads
  const int tcol = (tid & 15) * TN;       // 16 col-groups
  const int trow = (tid >> 4) * TM;       // 16 row-groups
  float acc[TM][TN] = {};
  for (int k0 = 0; k0 < K; k0 += BK) {
    {
      // A tile: BM x BK = 1024 elems, one float4 per thread
      int row = tid >> 2;
      int kk  = (tid & 3) * 4;
      int gr  = bm + row;
      float4 v = make_float4(0.f, 0.f, 0.f, 0.f);
      if (gr < M) v = *reinterpret_cast<const float4*>(A + (size_t)gr * K + k0 + kk);
      if (FUSE_IN) {
        v.x = fmaxf(v.x + bias_in[k0 + kk + 0], 0.f);
        v.y = fmaxf(v.y + bias_in[k0 + kk + 1], 0.f);
        v.z = fmaxf(v.z + bias_in[k0 + kk + 2], 0.f);
        v.w = fmaxf(v.w + bias_in[k0 + kk + 3], 0.f);
      }
      As[kk + 0][row] = v.x; As[kk + 1][row] = v.y;
      As[kk + 2][row] = v.z; As[kk + 3][row] = v.w;
    }
    {
      // B tile: BK x BN = 1024 elems
      int row = tid >> 4;
      int cc  = (tid & 15) * 4;
      float4 v = *reinterpret_cast<const float4*>(B + (size_t)(k0 + row) * Nc + bn + cc);
      Bs[row][cc + 0] = v.x; Bs[row][cc + 1] = v.y;
      Bs[row][cc + 2] = v.z; Bs[row][cc + 3] = v.w;
    }
    __syncthreads();
#pragma unroll
    for (int k = 0; k < BK; ++k) {
      float ra[TM], rb[TN];
#pragma unroll
      for (int i = 0; i < TM; ++i) ra[i] = As[k][trow + i];
#pragma unroll
      for (int j = 0; j < TN; ++j) rb[j] = Bs[k][tcol + j];
#pragma unroll
      for (int i = 0; i < TM; ++i)
#pragma unroll
        for (int j = 0; j < TN; ++j)
          acc[i][j] = fmaf(ra[i], rb[j], acc[i][j]);
    }
    __syncthreads();
  }
#pragma unroll
  for (int i = 0; i < TM; ++i) {
    int gr = bm + trow + i;
    if (gr >= M) continue;
    float4 v = make_float4(acc[i][0], acc[i][1], acc[i][2], acc[i][3]);
    *reinterpret_cast<float4*>(C + (size_t)gr * Nc + bn + tcol) = v;
    if (FUSE_SELF) {
      float s = dinv[gr]; s = s * s;
      float4 w = make_float4(v.x * s, v.y * s, v.z * s, v.w * s);
      *reinterpret_cast<float4*>(Cself + (size_t)gr * Nc + bn + tcol) = w;
    }
  }
}

// ---------------- edge scatter: out[dst] += dinv[src]*dinv[dst] * h[src] ----------------
// one wave (64 lanes) per edge; D/64 floats per lane
template<int D>
__global__ void k_scatter(const int* __restrict__ src, const int* __restrict__ dst,
                          const float* __restrict__ dinv, const float* __restrict__ h,
                          float* __restrict__ out, int E) {
  int gid  = blockIdx.x * blockDim.x + threadIdx.x;
  int wid  = gid >> 6;
  int lane = threadIdx.x & 63;
  if (wid >= E) return;
  int s = src[wid], d = dst[wid];
  float nrm = dinv[s] * dinv[d];
  const float* hp = h + (size_t)s * D;
  float* op = out + (size_t)d * D;
#pragma unroll
  for (int j = lane; j < D; j += 64)
    atomicAdd(&op[j], hp[j] * nrm);
}

// ---------------- graph mean-pool accumulate (batch is sorted) ----------------
__global__ void k_pool(const float* __restrict__ out2, const int* __restrict__ batch,
                       float* __restrict__ pool, int N, int nodesPerBlock) {
  __shared__ float lp[NG * DOUT];  // 16 KiB
  for (int i = threadIdx.x; i < NG * DOUT; i += blockDim.x) lp[i] = 0.f;
  __syncthreads();
  int col = threadIdx.x & 63;
  int w   = threadIdx.x >> 6;              // wave index 0..3
  int n0  = blockIdx.x * nodesPerBlock;
  int nend = min(n0 + nodesPerBlock, N);
  for (int n = n0 + w; n < nend; n += 4) {
    int g = batch[n];
    atomicAdd(&lp[g * DOUT + col], out2[(size_t)n * DOUT + col]);
  }
  __syncthreads();
  for (int i = threadIdx.x; i < NG * DOUT; i += blockDim.x) {
    float v = lp[i];
    if (v != 0.f) atomicAdd(&pool[i], v);
  }
}

__global__ void k_final(const float* __restrict__ pool, const float* __restrict__ cnt,
                        const float* __restrict__ b2, float* __restrict__ out) {
  int i = blockIdx.x * blockDim.x + threadIdx.x;
  if (i >= NG * DOUT) return;
  int g = i >> 6, c = i & 63;
  float cg = cnt[g];
  // reference: bias added per-node, then mean -> +b2 only when graph non-empty
  float v = (cg > 0.f) ? (pool[i] / cg + b2[c]) : 0.f;
  out[i] = 1.f / (1.f + expf(-v));
}

// ---------------- launcher ----------------
extern "C" void kernel_launch(void* const* d_in, const int* in_sizes, int n_in,
                              void* d_out, int out_size, void* d_ws, size_t ws_size,
                              hipStream_t stream) {
  const float* x    = (const float*)d_in[0];
  const int*   ei   = (const int*)d_in[1];
  const int*   bat  = (const int*)d_in[2];
  const float* W1   = (const float*)d_in[3];
  const float* b1   = (const float*)d_in[4];
  const float* W2   = (const float*)d_in[5];
  const float* b2   = (const float*)d_in[6];
  float* out = (float*)d_out;

  const int N = in_sizes[0] / DIN;   // 100000
  const int E = in_sizes[1] / 2;     // 600000
  const int* src = ei;
  const int* dst = ei + E;

  // workspace layout (floats)
  float* p    = (float*)d_ws;
  float* deg  = p;  p += N;
  float* dinv = p;  p += N;
  float* cnt  = p;  p += NG;               // cnt & pool contiguous (zeroed together)
  float* pool = p;  p += NG * DOUT;
  // align to 16B for float4 ops
  p = (float*)(((uintptr_t)p + 15) & ~(uintptr_t)15);
  float* h1   = p;  p += (size_t)N * DHID;
  float* out1 = p;  p += (size_t)N * DHID;
  // h1 region is dead after scatter1 -> reuse for layer-2 buffers
  float* h2   = h1;
  float* out2 = h1 + (size_t)N * DOUT;

  const int B256 = 256;
  auto cdiv = [](int a, int b) { return (a + b - 1) / b; };

  // 1) zero deg and cnt+pool
  k_zero<<<cdiv(N, B256), B256, 0, stream>>>(deg, N);
  k_zero<<<cdiv(NG + NG * DOUT, B256), B256, 0, stream>>>(cnt, NG + NG * DOUT);

  // 2) degrees, graph sizes, dinv
  k_deg<<<cdiv(E, B256), B256, 0, stream>>>(dst, deg, E);
  k_cnt<<<cdiv(N, B256), B256, 0, stream>>>(bat, cnt, N);
  k_dinv<<<cdiv(N, B256), B256, 0, stream>>>(deg, dinv, N);

  // 3) h1 = x @ W1 ; out1 = dinv^2 * h1 (self-loop term)
  sgemm_k<false, true><<<dim3(cdiv(N, 64), DHID / 64), B256, 0, stream>>>(
      x, W1, h1, out1, nullptr, dinv, N, DHID, DIN);

  // 4) edge messages layer 1 (atomic scatter into out1)
  k_scatter<DHID><<<cdiv(E * 64, B256), B256, 0, stream>>>(src, dst, dinv, h1, out1, E);

  // 5) h2 = relu(out1 + b1) @ W2 ; out2 = dinv^2 * h2
  sgemm_k<true, true><<<dim3(cdiv(N, 64), DOUT / 64), B256, 0, stream>>>(
      out1, W2, h2, out2, b1, dinv, N, DOUT, DHID);

  // 6) edge messages layer 2
  k_scatter<DOUT><<<cdiv(E * 64, B256), B256, 0, stream>>>(src, dst, dinv, h2, out2, E);

  // 7) graph mean pool + bias + sigmoid
  const int NPB = 2048;
  k_pool<<<cdiv(N, NPB), B256, 0, stream>>>(out2, bat, pool, N, NPB);
  k_final<<<cdiv(NG * DOUT, B256), B256, 0, stream>>>(pool, cnt, b2, out);
}

// Round 2
// 762.182 us; speedup vs baseline: 1.8208x; 1.8208x over previous
//
#include <hip/hip_runtime.h>
#include <hip/hip_bf16.h>
#include <math.h>

static constexpr int NG   = 64;   // graphs
static constexpr int DIN  = 128;
static constexpr int DHID = 128;
static constexpr int DOUT = 64;

// ---------------- small utility kernels ----------------

__global__ void k_zero(float* __restrict__ p, int n) {
  int i = blockIdx.x * blockDim.x + threadIdx.x;
  if (i < n) p[i] = 0.0f;
}

__global__ void k_deg(const int* __restrict__ dst, float* __restrict__ deg, int E) {
  int i = blockIdx.x * blockDim.x + threadIdx.x;
  if (i < E) atomicAdd(&deg[dst[i]], 1.0f);
}

// batch is sorted -> per-graph node count via binary search (NO atomics;
// the atomic version serialized ~100k same-address adds = 631 us)
__global__ void k_cnt_bs(const int* __restrict__ batch, float* __restrict__ cnt, int N) {
  int g = threadIdx.x;  // one thread per graph, single wave-pair block
  if (g >= NG) return;
  auto lower_bound = [&](int key) {
    int lo = 0, hi = N;
    while (lo < hi) {
      int mid = (lo + hi) >> 1;
      if (batch[mid] < key) lo = mid + 1; else hi = mid;
    }
    return lo;
  };
  int a = lower_bound(g);
  int b = lower_bound(g + 1);
  cnt[g] = (float)(b - a);
}

__global__ void k_dinv(const float* __restrict__ deg, float* __restrict__ dinv, int N) {
  int i = blockIdx.x * blockDim.x + threadIdx.x;
  if (i < N) dinv[i] = rsqrtf(deg[i] + 1.0f);  // +1 self-loop
}

// ---------------- tiled fp32 GEMM, C = A[M,K] @ B[K,Nc] ----------------
// FUSE_IN:   A element -> relu(a + bias_in[k])   (layer-2 input activation)
// FUSE_SELF: also write Cself[r][c] = dinv[r]^2 * acc  (self-loop message init)
template<bool FUSE_IN, bool FUSE_SELF>
__launch_bounds__(256)
__global__ void sgemm_k(const float* __restrict__ A, const float* __restrict__ B,
                        float* __restrict__ C, float* __restrict__ Cself,
                        const float* __restrict__ bias_in, const float* __restrict__ dinv,
                        int M, int Nc, int K) {
  constexpr int BM = 64, BN = 64, BK = 16, TM = 4, TN = 4;
  __shared__ float As[BK][BM];
  __shared__ float Bs[BK][BN];
  const int bm = blockIdx.x * BM;
  const int bn = blockIdx.y * BN;
  const int tid = threadIdx.x;            // 256 threads
  const int tcol = (tid & 15) * TN;       // 16 col-groups
  const int trow = (tid >> 4) * TM;       // 16 row-groups
  float acc[TM][TN] = {};
  for (int k0 = 0; k0 < K; k0 += BK) {
    {
      // A tile: BM x BK = 1024 elems, one float4 per thread
      int row = tid >> 2;
      int kk  = (tid & 3) * 4;
      int gr  = bm + row;
      float4 v = make_float4(0.f, 0.f, 0.f, 0.f);
      if (gr < M) v = *reinterpret_cast<const float4*>(A + (size_t)gr * K + k0 + kk);
      if (FUSE_IN) {
        v.x = fmaxf(v.x + bias_in[k0 + kk + 0], 0.f);
        v.y = fmaxf(v.y + bias_in[k0 + kk + 1], 0.f);
        v.z = fmaxf(v.z + bias_in[k0 + kk + 2], 0.f);
        v.w = fmaxf(v.w + bias_in[k0 + kk + 3], 0.f);
      }
      As[kk + 0][row] = v.x; As[kk + 1][row] = v.y;
      As[kk + 2][row] = v.z; As[kk + 3][row] = v.w;
    }
    {
      // B tile: BK x BN = 1024 elems
      int row = tid >> 4;
      int cc  = (tid & 15) * 4;
      float4 v = *reinterpret_cast<const float4*>(B + (size_t)(k0 + row) * Nc + bn + cc);
      Bs[row][cc + 0] = v.x; Bs[row][cc + 1] = v.y;
      Bs[row][cc + 2] = v.z; Bs[row][cc + 3] = v.w;
    }
    __syncthreads();
#pragma unroll
    for (int k = 0; k < BK; ++k) {
      float ra[TM], rb[TN];
#pragma unroll
      for (int i = 0; i < TM; ++i) ra[i] = As[k][trow + i];
#pragma unroll
      for (int j = 0; j < TN; ++j) rb[j] = Bs[k][tcol + j];
#pragma unroll
      for (int i = 0; i < TM; ++i)
#pragma unroll
        for (int j = 0; j < TN; ++j)
          acc[i][j] = fmaf(ra[i], rb[j], acc[i][j]);
    }
    __syncthreads();
  }
#pragma unroll
  for (int i = 0; i < TM; ++i) {
    int gr = bm + trow + i;
    if (gr >= M) continue;
    float4 v = make_float4(acc[i][0], acc[i][1], acc[i][2], acc[i][3]);
    *reinterpret_cast<float4*>(C + (size_t)gr * Nc + bn + tcol) = v;
    if (FUSE_SELF) {
      float s = dinv[gr]; s = s * s;
      float4 w = make_float4(v.x * s, v.y * s, v.z * s, v.w * s);
      *reinterpret_cast<float4*>(Cself + (size_t)gr * Nc + bn + tcol) = w;
    }
  }
}

// ---------------- edge scatter: out[dst] += dinv[src]*dinv[dst] * h[src] ----------------
// one wave (64 lanes) per edge; D/64 floats per lane
template<int D>
__global__ void k_scatter(const int* __restrict__ src, const int* __restrict__ dst,
                          const float* __restrict__ dinv, const float* __restrict__ h,
                          float* __restrict__ out, int E) {
  int gid  = blockIdx.x * blockDim.x + threadIdx.x;
  int wid  = gid >> 6;
  int lane = threadIdx.x & 63;
  if (wid >= E) return;
  int s = src[wid], d = dst[wid];
  float nrm = dinv[s] * dinv[d];
  const float* hp = h + (size_t)s * D;
  float* op = out + (size_t)d * D;
#pragma unroll
  for (int j = lane; j < D; j += 64)
    atomicAdd(&op[j], hp[j] * nrm);
}

// ---------------- graph mean-pool accumulate (batch is sorted) ----------------
__global__ void k_pool(const float* __restrict__ out2, const int* __restrict__ batch,
                       float* __restrict__ pool, int N, int nodesPerBlock) {
  __shared__ float lp[NG * DOUT];  // 16 KiB
  for (int i = threadIdx.x; i < NG * DOUT; i += blockDim.x) lp[i] = 0.f;
  __syncthreads();
  int col = threadIdx.x & 63;
  int w   = threadIdx.x >> 6;              // wave index 0..3
  int n0  = blockIdx.x * nodesPerBlock;
  int nend = min(n0 + nodesPerBlock, N);
  for (int n = n0 + w; n < nend; n += 4) {
    int g = batch[n];
    atomicAdd(&lp[g * DOUT + col], out2[(size_t)n * DOUT + col]);
  }
  __syncthreads();
  for (int i = threadIdx.x; i < NG * DOUT; i += blockDim.x) {
    float v = lp[i];
    if (v != 0.f) atomicAdd(&pool[i], v);
  }
}

__global__ void k_final(const float* __restrict__ pool, const float* __restrict__ cnt,
                        const float* __restrict__ b2, float* __restrict__ out) {
  int i = blockIdx.x * blockDim.x + threadIdx.x;
  if (i >= NG * DOUT) return;
  int g = i >> 6, c = i & 63;
  float cg = cnt[g];
  float v = (cg > 0.f) ? (pool[i] / cg + b2[c]) : 0.f;
  out[i] = 1.f / (1.f + expf(-v));
}

// ---------------- launcher ----------------
extern "C" void kernel_launch(void* const* d_in, const int* in_sizes, int n_in,
                              void* d_out, int out_size, void* d_ws, size_t ws_size,
                              hipStream_t stream) {
  const float* x    = (const float*)d_in[0];
  const int*   ei   = (const int*)d_in[1];
  const int*   bat  = (const int*)d_in[2];
  const float* W1   = (const float*)d_in[3];
  const float* b1   = (const float*)d_in[4];
  const float* W2   = (const float*)d_in[5];
  const float* b2   = (const float*)d_in[6];
  float* out = (float*)d_out;

  const int N = in_sizes[0] / DIN;   // 100000
  const int E = in_sizes[1] / 2;     // 600000
  const int* src = ei;
  const int* dst = ei + E;

  // workspace layout (floats)
  float* p    = (float*)d_ws;
  float* deg  = p;  p += N;
  float* dinv = p;  p += N;
  float* cnt  = p;  p += NG;
  float* pool = p;  p += NG * DOUT;
  p = (float*)(((uintptr_t)p + 15) & ~(uintptr_t)15);
  float* h1   = p;  p += (size_t)N * DHID;
  float* out1 = p;  p += (size_t)N * DHID;
  float* h2   = h1;                         // reuse (h1 dead after scatter1)
  float* out2 = h1 + (size_t)N * DOUT;

  const int B256 = 256;
  auto cdiv = [](int a, int b) { return (a + b - 1) / b; };

  // 1) zero deg and pool (cnt written directly by k_cnt_bs)
  k_zero<<<cdiv(N, B256), B256, 0, stream>>>(deg, N);
  k_zero<<<cdiv(NG * DOUT, B256), B256, 0, stream>>>(pool, NG * DOUT);

  // 2) degrees, graph sizes (binary search), dinv
  k_deg<<<cdiv(E, B256), B256, 0, stream>>>(dst, deg, E);
  k_cnt_bs<<<1, 128, 0, stream>>>(bat, cnt, N);
  k_dinv<<<cdiv(N, B256), B256, 0, stream>>>(deg, dinv, N);

  // 3) h1 = x @ W1 ; out1 = dinv^2 * h1 (self-loop term)
  sgemm_k<false, true><<<dim3(cdiv(N, 64), DHID / 64), B256, 0, stream>>>(
      x, W1, h1, out1, nullptr, dinv, N, DHID, DIN);

  // 4) edge messages layer 1 (atomic scatter into out1)
  k_scatter<DHID><<<cdiv(E * 64, B256), B256, 0, stream>>>(src, dst, dinv, h1, out1, E);

  // 5) h2 = relu(out1 + b1) @ W2 ; out2 = dinv^2 * h2
  sgemm_k<true, true><<<dim3(cdiv(N, 64), DOUT / 64), B256, 0, stream>>>(
      out1, W2, h2, out2, b1, dinv, N, DOUT, DHID);

  // 6) edge messages layer 2
  k_scatter<DOUT><<<cdiv(E * 64, B256), B256, 0, stream>>>(src, dst, dinv, h2, out2, E);

  // 7) graph mean pool + bias + sigmoid
  const int NPB = 2048;
  k_pool<<<cdiv(N, NPB), B256, 0, stream>>>(out2, bat, pool, N, NPB);
  k_final<<<cdiv(NG * DOUT, B256), B256, 0, stream>>>(pool, cnt, b2, out);
}

// Round 3
// 562.851 us; speedup vs baseline: 2.4657x; 1.3541x over previous
//
#include <hip/hip_runtime.h>
#include <hip/hip_bf16.h>
#include <math.h>

static constexpr int NG   = 64;   // graphs
static constexpr int DIN  = 128;
static constexpr int DHID = 128;
static constexpr int DOUT = 64;
static constexpr int SCAN_CH = 1024;  // elements per scan block (256 thr x 4)

// ---------------- small utility kernels ----------------

__global__ void k_zero(float* __restrict__ p, int n) {
  int i = blockIdx.x * blockDim.x + threadIdx.x;
  if (i < n) p[i] = 0.0f;
}

__global__ void k_degi(const int* __restrict__ dst, int* __restrict__ degc, int E) {
  int i = blockIdx.x * blockDim.x + threadIdx.x;
  if (i < E) atomicAdd(&degc[dst[i]], 1);
}

// batch is sorted -> per-graph node count via binary search (no atomics)
__global__ void k_cnt_bs(const int* __restrict__ batch, float* __restrict__ cnt, int N) {
  int g = threadIdx.x;
  if (g >= NG) return;
  auto lower_bound = [&](int key) {
    int lo = 0, hi = N;
    while (lo < hi) {
      int mid = (lo + hi) >> 1;
      if (batch[mid] < key) lo = mid + 1; else hi = mid;
    }
    return lo;
  };
  cnt[g] = (float)(lower_bound(g + 1) - lower_bound(g));
}

__global__ void k_dinv(const int* __restrict__ degc, float* __restrict__ dinv, int N) {
  int i = blockIdx.x * blockDim.x + threadIdx.x;
  if (i < N) dinv[i] = rsqrtf((float)degc[i] + 1.0f);  // +1 self-loop
}

// ---------------- exclusive prefix scan over degc -> rowptr (3 kernels) ----------------

__global__ void k_scanA(const int* __restrict__ in, int* __restrict__ bsum, int n) {
  __shared__ int s[256];
  int base = blockIdx.x * SCAN_CH;
  int t = threadIdx.x;
  int sum = 0;
#pragma unroll
  for (int k = 0; k < 4; ++k) {
    int i = base + t * 4 + k;
    if (i < n) sum += in[i];
  }
  s[t] = sum; __syncthreads();
  for (int off = 128; off > 0; off >>= 1) {
    if (t < off) s[t] += s[t + off];
    __syncthreads();
  }
  if (t == 0) bsum[blockIdx.x] = s[0];
}

__global__ void k_scanB(const int* __restrict__ bsum, int* __restrict__ boff, int nb) {
  __shared__ int s[128];
  int t = threadIdx.x;  // 128 threads, nb <= 128
  int mine = (t < nb) ? bsum[t] : 0;
  s[t] = mine; __syncthreads();
  for (int off = 1; off < 128; off <<= 1) {
    int v = (t >= off) ? s[t - off] : 0;
    __syncthreads();
    s[t] += v;
    __syncthreads();
  }
  if (t < nb) boff[t] = s[t] - mine;  // exclusive
}

__global__ void k_scanC(const int* __restrict__ in, const int* __restrict__ boff,
                        int* __restrict__ rowptr, int* __restrict__ cursor, int n, int E) {
  __shared__ int s[256];
  int base = blockIdx.x * SCAN_CH;
  int t = threadIdx.x;
  int loc[4];
  int sum = 0;
#pragma unroll
  for (int k = 0; k < 4; ++k) {
    int i = base + t * 4 + k;
    loc[k] = (i < n) ? in[i] : 0;
    sum += loc[k];
  }
  s[t] = sum; __syncthreads();
  for (int off = 1; off < 256; off <<= 1) {
    int v = (t >= off) ? s[t - off] : 0;
    __syncthreads();
    s[t] += v;
    __syncthreads();
  }
  int run = s[t] - sum + boff[blockIdx.x];  // exclusive across grid
#pragma unroll
  for (int k = 0; k < 4; ++k) {
    int i = base + t * 4 + k;
    if (i < n) { rowptr[i] = run; cursor[i] = run; run += loc[k]; }
  }
  if (blockIdx.x == 0 && t == 0) rowptr[n] = E;
}

// slot-fill: col[pos] = src  (0.6M int atomics vs 77M float atomics of scatter)
__global__ void k_fill(const int* __restrict__ src, const int* __restrict__ dst,
                       int* __restrict__ cursor, int* __restrict__ col, int E) {
  int i = blockIdx.x * blockDim.x + threadIdx.x;
  if (i < E) {
    int pos = atomicAdd(&cursor[dst[i]], 1);
    col[pos] = src[i];
  }
}

// ---------------- tiled fp32 GEMM, C = A[M,K] @ B[K,Nc] ----------------
// FUSE_IN: A element -> relu(a + bias_in[k])
template<bool FUSE_IN>
__launch_bounds__(256)
__global__ void sgemm_k(const float* __restrict__ A, const float* __restrict__ B,
                        float* __restrict__ C, const float* __restrict__ bias_in,
                        int M, int Nc, int K) {
  constexpr int BM = 64, BN = 64, BK = 16, TM = 4, TN = 4;
  __shared__ float As[BK][BM];
  __shared__ float Bs[BK][BN];
  const int bm = blockIdx.x * BM;
  const int bn = blockIdx.y * BN;
  const int tid = threadIdx.x;
  const int tcol = (tid & 15) * TN;
  const int trow = (tid >> 4) * TM;
  float acc[TM][TN] = {};
  for (int k0 = 0; k0 < K; k0 += BK) {
    {
      int row = tid >> 2;
      int kk  = (tid & 3) * 4;
      int gr  = bm + row;
      float4 v = make_float4(0.f, 0.f, 0.f, 0.f);
      if (gr < M) v = *reinterpret_cast<const float4*>(A + (size_t)gr * K + k0 + kk);
      if (FUSE_IN) {
        v.x = fmaxf(v.x + bias_in[k0 + kk + 0], 0.f);
        v.y = fmaxf(v.y + bias_in[k0 + kk + 1], 0.f);
        v.z = fmaxf(v.z + bias_in[k0 + kk + 2], 0.f);
        v.w = fmaxf(v.w + bias_in[k0 + kk + 3], 0.f);
      }
      As[kk + 0][row] = v.x; As[kk + 1][row] = v.y;
      As[kk + 2][row] = v.z; As[kk + 3][row] = v.w;
    }
    {
      int row = tid >> 4;
      int cc  = (tid & 15) * 4;
      float4 v = *reinterpret_cast<const float4*>(B + (size_t)(k0 + row) * Nc + bn + cc);
      Bs[row][cc + 0] = v.x; Bs[row][cc + 1] = v.y;
      Bs[row][cc + 2] = v.z; Bs[row][cc + 3] = v.w;
    }
    __syncthreads();
#pragma unroll
    for (int k = 0; k < BK; ++k) {
      float ra[TM], rb[TN];
#pragma unroll
      for (int i = 0; i < TM; ++i) ra[i] = As[k][trow + i];
#pragma unroll
      for (int j = 0; j < TN; ++j) rb[j] = Bs[k][tcol + j];
#pragma unroll
      for (int i = 0; i < TM; ++i)
#pragma unroll
        for (int j = 0; j < TN; ++j)
          acc[i][j] = fmaf(ra[i], rb[j], acc[i][j]);
    }
    __syncthreads();
  }
#pragma unroll
  for (int i = 0; i < TM; ++i) {
    int gr = bm + trow + i;
    if (gr >= M) continue;
    float4 v = make_float4(acc[i][0], acc[i][1], acc[i][2], acc[i][3]);
    *reinterpret_cast<float4*>(C + (size_t)gr * Nc + bn + tcol) = v;
  }
}

// ---------------- CSR gather: out[v] = dinv[v]^2*h[v] + sum_e dinv[col]*dinv[v]*h[col] ----
// one wave per node, D/64 floats per lane; atomic-free, each output written once
template<int D>
__global__ void k_gather(const int* __restrict__ rowptr, const int* __restrict__ col,
                         const float* __restrict__ dinv, const float* __restrict__ h,
                         float* __restrict__ outp, int N) {
  int wid  = (blockIdx.x * blockDim.x + threadIdx.x) >> 6;
  int lane = threadIdx.x & 63;
  if (wid >= N) return;
  const int v = wid;
  float dv = dinv[v];
  int beg = rowptr[v], end = rowptr[v + 1];
  constexpr int PER = D / 64;
  float acc[PER];
  const float* hv = h + (size_t)v * D;
#pragma unroll
  for (int p = 0; p < PER; ++p) acc[p] = dv * dv * hv[lane + 64 * p];
  for (int j = beg; j < end; ++j) {
    int s = col[j];
    float nrm = dinv[s] * dv;
    const float* hs = h + (size_t)s * D;
#pragma unroll
    for (int p = 0; p < PER; ++p) acc[p] = fmaf(nrm, hs[lane + 64 * p], acc[p]);
  }
  float* op = outp + (size_t)v * D;
#pragma unroll
  for (int p = 0; p < PER; ++p) op[lane + 64 * p] = acc[p];
}

// ---------------- graph mean-pool accumulate (batch is sorted) ----------------
__global__ void k_pool(const float* __restrict__ out2, const int* __restrict__ batch,
                       float* __restrict__ pool, int N, int nodesPerBlock) {
  __shared__ float lp[NG * DOUT];  // 16 KiB
  for (int i = threadIdx.x; i < NG * DOUT; i += blockDim.x) lp[i] = 0.f;
  __syncthreads();
  int col = threadIdx.x & 63;
  int w   = threadIdx.x >> 6;
  int n0  = blockIdx.x * nodesPerBlock;
  int nend = min(n0 + nodesPerBlock, N);
  for (int n = n0 + w; n < nend; n += 4) {
    int g = batch[n];
    atomicAdd(&lp[g * DOUT + col], out2[(size_t)n * DOUT + col]);
  }
  __syncthreads();
  for (int i = threadIdx.x; i < NG * DOUT; i += blockDim.x) {
    float v = lp[i];
    if (v != 0.f) atomicAdd(&pool[i], v);
  }
}

__global__ void k_final(const float* __restrict__ pool, const float* __restrict__ cnt,
                        const float* __restrict__ b2, float* __restrict__ out) {
  int i = blockIdx.x * blockDim.x + threadIdx.x;
  if (i >= NG * DOUT) return;
  int g = i >> 6, c = i & 63;
  float cg = cnt[g];
  float v = (cg > 0.f) ? (pool[i] / cg + b2[c]) : 0.f;
  out[i] = 1.f / (1.f + expf(-v));
}

// ---------------- launcher ----------------
extern "C" void kernel_launch(void* const* d_in, const int* in_sizes, int n_in,
                              void* d_out, int out_size, void* d_ws, size_t ws_size,
                              hipStream_t stream) {
  const float* x    = (const float*)d_in[0];
  const int*   ei   = (const int*)d_in[1];
  const int*   bat  = (const int*)d_in[2];
  const float* W1   = (const float*)d_in[3];
  const float* b1   = (const float*)d_in[4];
  const float* W2   = (const float*)d_in[5];
  const float* b2   = (const float*)d_in[6];
  float* out = (float*)d_out;

  const int N = in_sizes[0] / DIN;   // 100000
  const int E = in_sizes[1] / 2;     // 600000
  const int* src = ei;
  const int* dst = ei + E;

  // workspace layout
  char* wp = (char*)d_ws;
  auto alloc = [&](size_t bytes) { char* r = wp; wp += (bytes + 15) & ~(size_t)15; return r; };
  int*   degc   = (int*)  alloc(sizeof(int) * N);
  int*   rowptr = (int*)  alloc(sizeof(int) * (N + 1));
  int*   cursor = (int*)  alloc(sizeof(int) * (N + 1));
  int*   col    = (int*)  alloc(sizeof(int) * E);
  int*   bsum   = (int*)  alloc(sizeof(int) * 128);
  int*   boff   = (int*)  alloc(sizeof(int) * 128);
  float* dinv   = (float*)alloc(sizeof(float) * N);
  float* cnt    = (float*)alloc(sizeof(float) * NG);
  float* pool   = (float*)alloc(sizeof(float) * NG * DOUT);
  float* h1     = (float*)alloc(sizeof(float) * (size_t)N * DHID);
  float* out1   = (float*)alloc(sizeof(float) * (size_t)N * DHID);
  float* h2     = h1;                        // h1 dead after gather1
  float* out2   = h1 + (size_t)N * DOUT;

  const int B256 = 256;
  auto cdiv = [](int a, int b) { return (a + b - 1) / b; };
  const int nScanB = cdiv(N, SCAN_CH);       // 98 <= 128

  // 1) zero degc (int zeros == float zeros bitwise) and pool
  k_zero<<<cdiv(N, B256), B256, 0, stream>>>((float*)degc, N);
  k_zero<<<cdiv(NG * DOUT, B256), B256, 0, stream>>>(pool, NG * DOUT);

  // 2) CSR build: in-degree -> scan -> slot fill; plus cnt and dinv
  k_degi<<<cdiv(E, B256), B256, 0, stream>>>(dst, degc, E);
  k_cnt_bs<<<1, 128, 0, stream>>>(bat, cnt, N);
  k_scanA<<<nScanB, 256, 0, stream>>>(degc, bsum, N);
  k_scanB<<<1, 128, 0, stream>>>(bsum, boff, nScanB);
  k_scanC<<<nScanB, 256, 0, stream>>>(degc, boff, rowptr, cursor, N, E);
  k_fill<<<cdiv(E, B256), B256, 0, stream>>>(src, dst, cursor, col, E);
  k_dinv<<<cdiv(N, B256), B256, 0, stream>>>(degc, dinv, N);

  // 3) h1 = x @ W1
  sgemm_k<false><<<dim3(cdiv(N, 64), DHID / 64), B256, 0, stream>>>(
      x, W1, h1, nullptr, N, DHID, DIN);

  // 4) layer-1 propagate: atomic-free CSR gather
  k_gather<DHID><<<cdiv(N * 64, B256), B256, 0, stream>>>(rowptr, col, dinv, h1, out1, N);

  // 5) h2 = relu(out1 + b1) @ W2
  sgemm_k<true><<<dim3(cdiv(N, 64), DOUT / 64), B256, 0, stream>>>(
      out1, W2, h2, b1, N, DOUT, DHID);

  // 6) layer-2 propagate
  k_gather<DOUT><<<cdiv(N * 64, B256), B256, 0, stream>>>(rowptr, col, dinv, h2, out2, N);

  // 7) graph mean pool + bias + sigmoid
  const int NPB = 2048;
  k_pool<<<cdiv(N, NPB), B256, 0, stream>>>(out2, bat, pool, N, NPB);
  k_final<<<cdiv(NG * DOUT, B256), B256, 0, stream>>>(pool, cnt, b2, out);
}

// Round 4
// 398.983 us; speedup vs baseline: 3.4783x; 1.4107x over previous
//
#include <hip/hip_runtime.h>
#include <hip/hip_bf16.h>
#include <math.h>

static constexpr int NG   = 64;   // graphs
static constexpr int DIN  = 128;
static constexpr int DHID = 128;
static constexpr int DOUT = 64;
static constexpr int SCAN_CH = 1024;  // elements per scan block (256 thr x 4)

// ---------------- small utility kernels ----------------

__global__ void k_zero(float* __restrict__ p, int n) {
  int i = blockIdx.x * blockDim.x + threadIdx.x;
  if (i < n) p[i] = 0.0f;
}

__global__ void k_degi(const int* __restrict__ dst, int* __restrict__ degc, int E) {
  int i = blockIdx.x * blockDim.x + threadIdx.x;
  if (i < E) atomicAdd(&degc[dst[i]], 1);
}

// batch is sorted -> per-graph node count via binary search (no atomics)
__global__ void k_cnt_bs(const int* __restrict__ batch, float* __restrict__ cnt, int N) {
  int g = threadIdx.x;
  if (g >= NG) return;
  auto lower_bound = [&](int key) {
    int lo = 0, hi = N;
    while (lo < hi) {
      int mid = (lo + hi) >> 1;
      if (batch[mid] < key) lo = mid + 1; else hi = mid;
    }
    return lo;
  };
  cnt[g] = (float)(lower_bound(g + 1) - lower_bound(g));
}

__global__ void k_dinv(const int* __restrict__ degc, float* __restrict__ dinv, int N) {
  int i = blockIdx.x * blockDim.x + threadIdx.x;
  if (i < N) dinv[i] = rsqrtf((float)degc[i] + 1.0f);  // +1 self-loop
}

// ---------------- exclusive prefix scan over degc -> rowptr (3 kernels) ----------------

__global__ void k_scanA(const int* __restrict__ in, int* __restrict__ bsum, int n) {
  __shared__ int s[256];
  int base = blockIdx.x * SCAN_CH;
  int t = threadIdx.x;
  int sum = 0;
#pragma unroll
  for (int k = 0; k < 4; ++k) {
    int i = base + t * 4 + k;
    if (i < n) sum += in[i];
  }
  s[t] = sum; __syncthreads();
  for (int off = 128; off > 0; off >>= 1) {
    if (t < off) s[t] += s[t + off];
    __syncthreads();
  }
  if (t == 0) bsum[blockIdx.x] = s[0];
}

__global__ void k_scanB(const int* __restrict__ bsum, int* __restrict__ boff, int nb) {
  __shared__ int s[128];
  int t = threadIdx.x;  // 128 threads, nb <= 128
  int mine = (t < nb) ? bsum[t] : 0;
  s[t] = mine; __syncthreads();
  for (int off = 1; off < 128; off <<= 1) {
    int v = (t >= off) ? s[t - off] : 0;
    __syncthreads();
    s[t] += v;
    __syncthreads();
  }
  if (t < nb) boff[t] = s[t] - mine;  // exclusive
}

__global__ void k_scanC(const int* __restrict__ in, const int* __restrict__ boff,
                        int* __restrict__ rowptr, int* __restrict__ cursor, int n, int E) {
  __shared__ int s[256];
  int base = blockIdx.x * SCAN_CH;
  int t = threadIdx.x;
  int loc[4];
  int sum = 0;
#pragma unroll
  for (int k = 0; k < 4; ++k) {
    int i = base + t * 4 + k;
    loc[k] = (i < n) ? in[i] : 0;
    sum += loc[k];
  }
  s[t] = sum; __syncthreads();
  for (int off = 1; off < 256; off <<= 1) {
    int v = (t >= off) ? s[t - off] : 0;
    __syncthreads();
    s[t] += v;
    __syncthreads();
  }
  int run = s[t] - sum + boff[blockIdx.x];  // exclusive across grid
#pragma unroll
  for (int k = 0; k < 4; ++k) {
    int i = base + t * 4 + k;
    if (i < n) { rowptr[i] = run; cursor[i] = run; run += loc[k]; }
  }
  if (blockIdx.x == 0 && t == 0) rowptr[n] = E;
}

// slot-fill: col[pos] = src
__global__ void k_fill(const int* __restrict__ src, const int* __restrict__ dst,
                       int* __restrict__ cursor, int* __restrict__ col, int E) {
  int i = blockIdx.x * blockDim.x + threadIdx.x;
  if (i < E) {
    int pos = atomicAdd(&cursor[dst[i]], 1);
    col[pos] = src[i];
  }
}

// ---------------- tiled fp32 GEMM, C = A[M,K] @ B[K,Nc] ----------------
// FUSE_IN: A element -> relu(a + bias_in[k])
template<bool FUSE_IN>
__launch_bounds__(256)
__global__ void sgemm_k(const float* __restrict__ A, const float* __restrict__ B,
                        float* __restrict__ C, const float* __restrict__ bias_in,
                        int M, int Nc, int K) {
  constexpr int BM = 64, BN = 64, BK = 16, TM = 4, TN = 4;
  __shared__ float As[BK][BM];
  __shared__ float Bs[BK][BN];
  const int bm = blockIdx.x * BM;
  const int bn = blockIdx.y * BN;
  const int tid = threadIdx.x;
  const int tcol = (tid & 15) * TN;
  const int trow = (tid >> 4) * TM;
  float acc[TM][TN] = {};
  for (int k0 = 0; k0 < K; k0 += BK) {
    {
      int row = tid >> 2;
      int kk  = (tid & 3) * 4;
      int gr  = bm + row;
      float4 v = make_float4(0.f, 0.f, 0.f, 0.f);
      if (gr < M) v = *reinterpret_cast<const float4*>(A + (size_t)gr * K + k0 + kk);
      if (FUSE_IN) {
        v.x = fmaxf(v.x + bias_in[k0 + kk + 0], 0.f);
        v.y = fmaxf(v.y + bias_in[k0 + kk + 1], 0.f);
        v.z = fmaxf(v.z + bias_in[k0 + kk + 2], 0.f);
        v.w = fmaxf(v.w + bias_in[k0 + kk + 3], 0.f);
      }
      As[kk + 0][row] = v.x; As[kk + 1][row] = v.y;
      As[kk + 2][row] = v.z; As[kk + 3][row] = v.w;
    }
    {
      int row = tid >> 4;
      int cc  = (tid & 15) * 4;
      float4 v = *reinterpret_cast<const float4*>(B + (size_t)(k0 + row) * Nc + bn + cc);
      Bs[row][cc + 0] = v.x; Bs[row][cc + 1] = v.y;
      Bs[row][cc + 2] = v.z; Bs[row][cc + 3] = v.w;
    }
    __syncthreads();
#pragma unroll
    for (int k = 0; k < BK; ++k) {
      float ra[TM], rb[TN];
#pragma unroll
      for (int i = 0; i < TM; ++i) ra[i] = As[k][trow + i];
#pragma unroll
      for (int j = 0; j < TN; ++j) rb[j] = Bs[k][tcol + j];
#pragma unroll
      for (int i = 0; i < TM; ++i)
#pragma unroll
        for (int j = 0; j < TN; ++j)
          acc[i][j] = fmaf(ra[i], rb[j], acc[i][j]);
    }
    __syncthreads();
  }
#pragma unroll
  for (int i = 0; i < TM; ++i) {
    int gr = bm + trow + i;
    if (gr >= M) continue;
    float4 v = make_float4(acc[i][0], acc[i][1], acc[i][2], acc[i][3]);
    *reinterpret_cast<float4*>(C + (size_t)gr * Nc + bn + tcol) = v;
  }
}

// ---------------- CSR gather: out[v] = dinv[v]^2*h[v] + sum_e dinv[col]*dinv[v]*h[col] ----
template<int D>
__global__ void k_gather(const int* __restrict__ rowptr, const int* __restrict__ col,
                         const float* __restrict__ dinv, const float* __restrict__ h,
                         float* __restrict__ outp, int N) {
  int wid  = (blockIdx.x * blockDim.x + threadIdx.x) >> 6;
  int lane = threadIdx.x & 63;
  if (wid >= N) return;
  const int v = wid;
  float dv = dinv[v];
  int beg = rowptr[v], end = rowptr[v + 1];
  constexpr int PER = D / 64;
  float acc[PER];
  const float* hv = h + (size_t)v * D;
#pragma unroll
  for (int p = 0; p < PER; ++p) acc[p] = dv * dv * hv[lane + 64 * p];
  for (int j = beg; j < end; ++j) {
    int s = col[j];
    float nrm = dinv[s] * dv;
    const float* hs = h + (size_t)s * D;
#pragma unroll
    for (int p = 0; p < PER; ++p) acc[p] = fmaf(nrm, hs[lane + 64 * p], acc[p]);
  }
  float* op = outp + (size_t)v * D;
#pragma unroll
  for (int p = 0; p < PER; ++p) op[lane + 64 * p] = acc[p];
}

// ---------------- graph mean-pool: batch sorted -> segmented column sum ----------------
// one wave per contiguous node range; lane = column; register accumulate,
// global atomic flush only at graph boundaries (~1.5 flushes/wave)
__global__ void k_pool2(const float* __restrict__ out2, const int* __restrict__ batch,
                        float* __restrict__ pool, int N) {
  int wid  = (blockIdx.x * blockDim.x + threadIdx.x) >> 6;
  int lane = threadIdx.x & 63;
  int nw   = (gridDim.x * blockDim.x) >> 6;
  int per  = (N + nw - 1) / nw;
  int n0 = wid * per, n1 = min(n0 + per, N);
  if (n0 >= n1) return;
  int g = batch[n0];
  float acc = 0.f;
  int n = n0;
  while (n < n1) {
    // fast path: 4 rows, all same graph (batch sorted => batch[n+3]==g implies run)
    if (n + 4 <= n1 && batch[n + 3] == g) {
      float a0 = out2[(size_t)(n + 0) * DOUT + lane];
      float a1 = out2[(size_t)(n + 1) * DOUT + lane];
      float a2 = out2[(size_t)(n + 2) * DOUT + lane];
      float a3 = out2[(size_t)(n + 3) * DOUT + lane];
      acc += (a0 + a1) + (a2 + a3);
      n += 4;
    } else {
      int bg = batch[n];
      if (bg != g) { atomicAdd(&pool[g * DOUT + lane], acc); acc = 0.f; g = bg; }
      acc += out2[(size_t)n * DOUT + lane];
      ++n;
    }
  }
  atomicAdd(&pool[g * DOUT + lane], acc);
}

__global__ void k_final(const float* __restrict__ pool, const float* __restrict__ cnt,
                        const float* __restrict__ b2, float* __restrict__ out) {
  int i = blockIdx.x * blockDim.x + threadIdx.x;
  if (i >= NG * DOUT) return;
  int g = i >> 6, c = i & 63;
  float cg = cnt[g];
  float v = (cg > 0.f) ? (pool[i] / cg + b2[c]) : 0.f;
  out[i] = 1.f / (1.f + expf(-v));
}

// ---------------- launcher ----------------
extern "C" void kernel_launch(void* const* d_in, const int* in_sizes, int n_in,
                              void* d_out, int out_size, void* d_ws, size_t ws_size,
                              hipStream_t stream) {
  const float* x    = (const float*)d_in[0];
  const int*   ei   = (const int*)d_in[1];
  const int*   bat  = (const int*)d_in[2];
  const float* W1   = (const float*)d_in[3];
  const float* b1   = (const float*)d_in[4];
  const float* W2   = (const float*)d_in[5];
  const float* b2   = (const float*)d_in[6];
  float* out = (float*)d_out;

  const int N = in_sizes[0] / DIN;   // 100000
  const int E = in_sizes[1] / 2;     // 600000
  const int* src = ei;
  const int* dst = ei + E;

  // workspace layout
  char* wp = (char*)d_ws;
  auto alloc = [&](size_t bytes) { char* r = wp; wp += (bytes + 15) & ~(size_t)15; return r; };
  int*   degc   = (int*)  alloc(sizeof(int) * N);
  int*   rowptr = (int*)  alloc(sizeof(int) * (N + 1));
  int*   cursor = (int*)  alloc(sizeof(int) * (N + 1));
  int*   col    = (int*)  alloc(sizeof(int) * E);
  int*   bsum   = (int*)  alloc(sizeof(int) * 128);
  int*   boff   = (int*)  alloc(sizeof(int) * 128);
  float* dinv   = (float*)alloc(sizeof(float) * N);
  float* cnt    = (float*)alloc(sizeof(float) * NG);
  float* pool   = (float*)alloc(sizeof(float) * NG * DOUT);
  float* h1     = (float*)alloc(sizeof(float) * (size_t)N * DHID);
  float* out1   = (float*)alloc(sizeof(float) * (size_t)N * DHID);
  float* h2     = h1;                        // h1 dead after gather1
  float* out2   = h1 + (size_t)N * DOUT;

  const int B256 = 256;
  auto cdiv = [](int a, int b) { return (a + b - 1) / b; };
  const int nScanB = cdiv(N, SCAN_CH);       // 98 <= 128

  // 1) zero degc and pool
  k_zero<<<cdiv(N, B256), B256, 0, stream>>>((float*)degc, N);
  k_zero<<<cdiv(NG * DOUT, B256), B256, 0, stream>>>(pool, NG * DOUT);

  // 2) CSR build: in-degree -> scan -> slot fill; plus cnt and dinv
  k_degi<<<cdiv(E, B256), B256, 0, stream>>>(dst, degc, E);
  k_cnt_bs<<<1, 128, 0, stream>>>(bat, cnt, N);
  k_scanA<<<nScanB, 256, 0, stream>>>(degc, bsum, N);
  k_scanB<<<1, 128, 0, stream>>>(bsum, boff, nScanB);
  k_scanC<<<nScanB, 256, 0, stream>>>(degc, boff, rowptr, cursor, N, E);
  k_fill<<<cdiv(E, B256), B256, 0, stream>>>(src, dst, cursor, col, E);
  k_dinv<<<cdiv(N, B256), B256, 0, stream>>>(degc, dinv, N);

  // 3) h1 = x @ W1
  sgemm_k<false><<<dim3(cdiv(N, 64), DHID / 64), B256, 0, stream>>>(
      x, W1, h1, nullptr, N, DHID, DIN);

  // 4) layer-1 propagate: atomic-free CSR gather
  k_gather<DHID><<<cdiv(N * 64, B256), B256, 0, stream>>>(rowptr, col, dinv, h1, out1, N);

  // 5) h2 = relu(out1 + b1) @ W2
  sgemm_k<true><<<dim3(cdiv(N, 64), DOUT / 64), B256, 0, stream>>>(
      out1, W2, h2, b1, N, DOUT, DHID);

  // 6) layer-2 propagate
  k_gather<DOUT><<<cdiv(N * 64, B256), B256, 0, stream>>>(rowptr, col, dinv, h2, out2, N);

  // 7) graph mean pool + bias + sigmoid (1024 blocks -> 4096 waves, ~25 rows each)
  k_pool2<<<1024, B256, 0, stream>>>(out2, bat, pool, N);
  k_final<<<cdiv(NG * DOUT, B256), B256, 0, stream>>>(pool, cnt, b2, out);
}

// Round 5
// 347.884 us; speedup vs baseline: 3.9893x; 1.1469x over previous
//
#include <hip/hip_runtime.h>
#include <hip/hip_bf16.h>
#include <math.h>

static constexpr int NG   = 64;   // graphs
static constexpr int DIN  = 128;
static constexpr int DHID = 128;
static constexpr int DOUT = 64;
static constexpr int SCAN_CH = 1024;  // elements per scan block (256 thr x 4)

__device__ __forceinline__ float bf2f(unsigned short u) {
  unsigned int x = ((unsigned int)u) << 16;
  return __builtin_bit_cast(float, x);
}
__device__ __forceinline__ unsigned short f2bf(float f) {  // round-to-nearest-even
  unsigned int x = __builtin_bit_cast(unsigned int, f);
  unsigned int r = x + 0x7fffu + ((x >> 16) & 1u);
  return (unsigned short)(r >> 16);
}

// ---------------- small utility kernels ----------------

__global__ void k_zero(float* __restrict__ p, int n) {
  int i = blockIdx.x * blockDim.x + threadIdx.x;
  if (i < n) p[i] = 0.0f;
}

__global__ void k_degi(const int* __restrict__ dst, int* __restrict__ degc, int E) {
  int i = blockIdx.x * blockDim.x + threadIdx.x;
  if (i < E) atomicAdd(&degc[dst[i]], 1);
}

// batch is sorted -> per-graph node count via binary search (no atomics)
__global__ void k_cnt_bs(const int* __restrict__ batch, float* __restrict__ cnt, int N) {
  int g = threadIdx.x;
  if (g >= NG) return;
  auto lower_bound = [&](int key) {
    int lo = 0, hi = N;
    while (lo < hi) {
      int mid = (lo + hi) >> 1;
      if (batch[mid] < key) lo = mid + 1; else hi = mid;
    }
    return lo;
  };
  cnt[g] = (float)(lower_bound(g + 1) - lower_bound(g));
}

__global__ void k_dinv(const int* __restrict__ degc, float* __restrict__ dinv, int N) {
  int i = blockIdx.x * blockDim.x + threadIdx.x;
  if (i < N) dinv[i] = rsqrtf((float)degc[i] + 1.0f);  // +1 self-loop
}

// ---------------- exclusive prefix scan over degc -> rowptr (3 kernels) ----------------

__global__ void k_scanA(const int* __restrict__ in, int* __restrict__ bsum, int n) {
  __shared__ int s[256];
  int base = blockIdx.x * SCAN_CH;
  int t = threadIdx.x;
  int sum = 0;
#pragma unroll
  for (int k = 0; k < 4; ++k) {
    int i = base + t * 4 + k;
    if (i < n) sum += in[i];
  }
  s[t] = sum; __syncthreads();
  for (int off = 128; off > 0; off >>= 1) {
    if (t < off) s[t] += s[t + off];
    __syncthreads();
  }
  if (t == 0) bsum[blockIdx.x] = s[0];
}

__global__ void k_scanB(const int* __restrict__ bsum, int* __restrict__ boff, int nb) {
  __shared__ int s[128];
  int t = threadIdx.x;  // 128 threads, nb <= 128
  int mine = (t < nb) ? bsum[t] : 0;
  s[t] = mine; __syncthreads();
  for (int off = 1; off < 128; off <<= 1) {
    int v = (t >= off) ? s[t - off] : 0;
    __syncthreads();
    s[t] += v;
    __syncthreads();
  }
  if (t < nb) boff[t] = s[t] - mine;  // exclusive
}

__global__ void k_scanC(const int* __restrict__ in, const int* __restrict__ boff,
                        int* __restrict__ rowptr, int* __restrict__ cursor, int n, int E) {
  __shared__ int s[256];
  int base = blockIdx.x * SCAN_CH;
  int t = threadIdx.x;
  int loc[4];
  int sum = 0;
#pragma unroll
  for (int k = 0; k < 4; ++k) {
    int i = base + t * 4 + k;
    loc[k] = (i < n) ? in[i] : 0;
    sum += loc[k];
  }
  s[t] = sum; __syncthreads();
  for (int off = 1; off < 256; off <<= 1) {
    int v = (t >= off) ? s[t - off] : 0;
    __syncthreads();
    s[t] += v;
    __syncthreads();
  }
  int run = s[t] - sum + boff[blockIdx.x];  // exclusive across grid
#pragma unroll
  for (int k = 0; k < 4; ++k) {
    int i = base + t * 4 + k;
    if (i < n) { rowptr[i] = run; cursor[i] = run; run += loc[k]; }
  }
  if (blockIdx.x == 0 && t == 0) rowptr[n] = E;
}

// slot-fill: col[pos] = src
__global__ void k_fill(const int* __restrict__ src, const int* __restrict__ dst,
                       int* __restrict__ cursor, int* __restrict__ col, int E) {
  int i = blockIdx.x * blockDim.x + threadIdx.x;
  if (i < E) {
    int pos = atomicAdd(&cursor[dst[i]], 1);
    col[pos] = src[i];
  }
}

// ---------------- tiled fp32 GEMM, Cbf[r][c] = bf16( dinv[r] * (A@B)[r][c] ) ------------
// FUSE_IN: A element -> relu(a + bias_in[k])
template<bool FUSE_IN>
__launch_bounds__(256)
__global__ void sgemm_k(const float* __restrict__ A, const float* __restrict__ B,
                        unsigned short* __restrict__ Cbf, const float* __restrict__ bias_in,
                        const float* __restrict__ dinv, int M, int Nc, int K) {
  constexpr int BM = 64, BN = 64, BK = 16, TM = 4, TN = 4;
  __shared__ float As[BK][BM];
  __shared__ float Bs[BK][BN];
  const int bm = blockIdx.x * BM;
  const int bn = blockIdx.y * BN;
  const int tid = threadIdx.x;
  const int tcol = (tid & 15) * TN;
  const int trow = (tid >> 4) * TM;
  float acc[TM][TN] = {};
  for (int k0 = 0; k0 < K; k0 += BK) {
    {
      int row = tid >> 2;
      int kk  = (tid & 3) * 4;
      int gr  = bm + row;
      float4 v = make_float4(0.f, 0.f, 0.f, 0.f);
      if (gr < M) v = *reinterpret_cast<const float4*>(A + (size_t)gr * K + k0 + kk);
      if (FUSE_IN) {
        v.x = fmaxf(v.x + bias_in[k0 + kk + 0], 0.f);
        v.y = fmaxf(v.y + bias_in[k0 + kk + 1], 0.f);
        v.z = fmaxf(v.z + bias_in[k0 + kk + 2], 0.f);
        v.w = fmaxf(v.w + bias_in[k0 + kk + 3], 0.f);
      }
      As[kk + 0][row] = v.x; As[kk + 1][row] = v.y;
      As[kk + 2][row] = v.z; As[kk + 3][row] = v.w;
    }
    {
      int row = tid >> 4;
      int cc  = (tid & 15) * 4;
      float4 v = *reinterpret_cast<const float4*>(B + (size_t)(k0 + row) * Nc + bn + cc);
      Bs[row][cc + 0] = v.x; Bs[row][cc + 1] = v.y;
      Bs[row][cc + 2] = v.z; Bs[row][cc + 3] = v.w;
    }
    __syncthreads();
#pragma unroll
    for (int k = 0; k < BK; ++k) {
      float ra[TM], rb[TN];
#pragma unroll
      for (int i = 0; i < TM; ++i) ra[i] = As[k][trow + i];
#pragma unroll
      for (int j = 0; j < TN; ++j) rb[j] = Bs[k][tcol + j];
#pragma unroll
      for (int i = 0; i < TM; ++i)
#pragma unroll
        for (int j = 0; j < TN; ++j)
          acc[i][j] = fmaf(ra[i], rb[j], acc[i][j]);
    }
    __syncthreads();
  }
#pragma unroll
  for (int i = 0; i < TM; ++i) {
    int gr = bm + trow + i;
    if (gr >= M) continue;
    float s = dinv[gr];
    ushort4 w = make_ushort4(f2bf(acc[i][0] * s), f2bf(acc[i][1] * s),
                             f2bf(acc[i][2] * s), f2bf(acc[i][3] * s));
    *reinterpret_cast<ushort4*>(Cbf + (size_t)gr * Nc + bn + tcol) = w;
  }
}

// ---------------- CSR gather over pre-scaled bf16 rows ----------------
// out[v] = dinv[v] * ( hbf[v] + sum_{e} hbf[col[e]] )   (fp32 accumulate)
// D=128: 1 row/wave (64 lanes x ushort2); D=64: 2 rows/wave (half-waves) + shfl combine
template<int D>
__global__ void k_gather_bf(const int* __restrict__ rowptr, const int* __restrict__ col,
                            const float* __restrict__ dinv,
                            const unsigned short* __restrict__ hbf,
                            float* __restrict__ outp, int N) {
  constexpr int LPR = D / 2;       // lanes per row (ushort2 each)
  constexpr int RPW = 64 / LPR;    // rows per wave step (1 or 2)
  int wid  = (blockIdx.x * blockDim.x + threadIdx.x) >> 6;
  int lane = threadIdx.x & 63;
  if (wid >= N) return;
  const int v   = wid;
  const int sub = lane / LPR;
  const int li  = lane % LPR;
  const size_t eoff = 2 * li;
  int beg = rowptr[v], end = rowptr[v + 1];
  float a0 = 0.f, a1 = 0.f;
  if (sub == 0) {  // self term once
    ushort2 u = *reinterpret_cast<const ushort2*>(hbf + (size_t)v * D + eoff);
    a0 = bf2f(u.x); a1 = bf2f(u.y);
  }
  int j = beg + sub;
  // 4-deep unroll: independent row loads in flight
  for (; j + 3 * RPW < end; j += 4 * RPW) {
    int s0 = col[j], s1 = col[j + RPW], s2 = col[j + 2 * RPW], s3 = col[j + 3 * RPW];
    ushort2 u0 = *reinterpret_cast<const ushort2*>(hbf + (size_t)s0 * D + eoff);
    ushort2 u1 = *reinterpret_cast<const ushort2*>(hbf + (size_t)s1 * D + eoff);
    ushort2 u2 = *reinterpret_cast<const ushort2*>(hbf + (size_t)s2 * D + eoff);
    ushort2 u3 = *reinterpret_cast<const ushort2*>(hbf + (size_t)s3 * D + eoff);
    a0 += (bf2f(u0.x) + bf2f(u1.x)) + (bf2f(u2.x) + bf2f(u3.x));
    a1 += (bf2f(u0.y) + bf2f(u1.y)) + (bf2f(u2.y) + bf2f(u3.y));
  }
  for (; j < end; j += RPW) {
    int s = col[j];
    ushort2 u = *reinterpret_cast<const ushort2*>(hbf + (size_t)s * D + eoff);
    a0 += bf2f(u.x); a1 += bf2f(u.y);
  }
  if constexpr (RPW == 2) {
    a0 += __shfl_xor(a0, 32, 64);
    a1 += __shfl_xor(a1, 32, 64);
  }
  if (sub == 0) {
    float dv = dinv[v];
    *reinterpret_cast<float2*>(outp + (size_t)v * D + eoff) = make_float2(dv * a0, dv * a1);
  }
}

// ---------------- graph mean-pool: batch sorted -> segmented column sum ----------------
__global__ void k_pool2(const float* __restrict__ out2, const int* __restrict__ batch,
                        float* __restrict__ pool, int N) {
  int wid  = (blockIdx.x * blockDim.x + threadIdx.x) >> 6;
  int lane = threadIdx.x & 63;
  int nw   = (gridDim.x * blockDim.x) >> 6;
  int per  = (N + nw - 1) / nw;
  int n0 = wid * per, n1 = min(n0 + per, N);
  if (n0 >= n1) return;
  int g = batch[n0];
  float acc = 0.f;
  int n = n0;
  while (n < n1) {
    if (n + 4 <= n1 && batch[n + 3] == g) {
      float a0 = out2[(size_t)(n + 0) * DOUT + lane];
      float a1 = out2[(size_t)(n + 1) * DOUT + lane];
      float a2 = out2[(size_t)(n + 2) * DOUT + lane];
      float a3 = out2[(size_t)(n + 3) * DOUT + lane];
      acc += (a0 + a1) + (a2 + a3);
      n += 4;
    } else {
      int bg = batch[n];
      if (bg != g) { atomicAdd(&pool[g * DOUT + lane], acc); acc = 0.f; g = bg; }
      acc += out2[(size_t)n * DOUT + lane];
      ++n;
    }
  }
  atomicAdd(&pool[g * DOUT + lane], acc);
}

__global__ void k_final(const float* __restrict__ pool, const float* __restrict__ cnt,
                        const float* __restrict__ b2, float* __restrict__ out) {
  int i = blockIdx.x * blockDim.x + threadIdx.x;
  if (i >= NG * DOUT) return;
  int g = i >> 6, c = i & 63;
  float cg = cnt[g];
  float v = (cg > 0.f) ? (pool[i] / cg + b2[c]) : 0.f;
  out[i] = 1.f / (1.f + expf(-v));
}

// ---------------- launcher ----------------
extern "C" void kernel_launch(void* const* d_in, const int* in_sizes, int n_in,
                              void* d_out, int out_size, void* d_ws, size_t ws_size,
                              hipStream_t stream) {
  const float* x    = (const float*)d_in[0];
  const int*   ei   = (const int*)d_in[1];
  const int*   bat  = (const int*)d_in[2];
  const float* W1   = (const float*)d_in[3];
  const float* b1   = (const float*)d_in[4];
  const float* W2   = (const float*)d_in[5];
  const float* b2   = (const float*)d_in[6];
  float* out = (float*)d_out;

  const int N = in_sizes[0] / DIN;   // 100000
  const int E = in_sizes[1] / 2;     // 600000
  const int* src = ei;
  const int* dst = ei + E;

  // workspace layout
  char* wp = (char*)d_ws;
  auto alloc = [&](size_t bytes) { char* r = wp; wp += (bytes + 15) & ~(size_t)15; return r; };
  int*   degc   = (int*)  alloc(sizeof(int) * N);
  int*   rowptr = (int*)  alloc(sizeof(int) * (N + 1));
  int*   cursor = (int*)  alloc(sizeof(int) * (N + 1));
  int*   col    = (int*)  alloc(sizeof(int) * E);
  int*   bsum   = (int*)  alloc(sizeof(int) * 128);
  int*   boff   = (int*)  alloc(sizeof(int) * 128);
  float* dinv   = (float*)alloc(sizeof(float) * N);
  float* cnt    = (float*)alloc(sizeof(float) * NG);
  float* pool   = (float*)alloc(sizeof(float) * NG * DOUT);
  unsigned short* hbf1 = (unsigned short*)alloc(sizeof(unsigned short) * (size_t)N * DHID);
  float* out1   = (float*)alloc(sizeof(float) * (size_t)N * DHID);
  unsigned short* hbf2 = hbf1;               // hbf1 dead after gather1
  float* out2   = out1;                      // out1 dead after sgemm2

  const int B256 = 256;
  auto cdiv = [](int a, int b) { return (a + b - 1) / b; };
  const int nScanB = cdiv(N, SCAN_CH);       // 98 <= 128

  // 1) zero degc and pool
  k_zero<<<cdiv(N, B256), B256, 0, stream>>>((float*)degc, N);
  k_zero<<<cdiv(NG * DOUT, B256), B256, 0, stream>>>(pool, NG * DOUT);

  // 2) CSR build: in-degree -> scan -> slot fill; plus cnt and dinv
  k_degi<<<cdiv(E, B256), B256, 0, stream>>>(dst, degc, E);
  k_cnt_bs<<<1, 128, 0, stream>>>(bat, cnt, N);
  k_scanA<<<nScanB, 256, 0, stream>>>(degc, bsum, N);
  k_scanB<<<1, 128, 0, stream>>>(bsum, boff, nScanB);
  k_scanC<<<nScanB, 256, 0, stream>>>(degc, boff, rowptr, cursor, N, E);
  k_fill<<<cdiv(E, B256), B256, 0, stream>>>(src, dst, cursor, col, E);
  k_dinv<<<cdiv(N, B256), B256, 0, stream>>>(degc, dinv, N);

  // 3) hbf1 = bf16( dinv * (x @ W1) )
  sgemm_k<false><<<dim3(cdiv(N, 64), DHID / 64), B256, 0, stream>>>(
      x, W1, hbf1, nullptr, dinv, N, DHID, DIN);

  // 4) layer-1 propagate: out1 = dinv * (self + neighbor sum)   [fp32]
  k_gather_bf<DHID><<<cdiv(N * 64, B256), B256, 0, stream>>>(rowptr, col, dinv, hbf1, out1, N);

  // 5) hbf2 = bf16( dinv * (relu(out1 + b1) @ W2) )
  sgemm_k<true><<<dim3(cdiv(N, 64), DOUT / 64), B256, 0, stream>>>(
      out1, W2, hbf2, b1, dinv, N, DOUT, DHID);

  // 6) layer-2 propagate
  k_gather_bf<DOUT><<<cdiv(N * 64, B256), B256, 0, stream>>>(rowptr, col, dinv, hbf2, out2, N);

  // 7) graph mean pool + bias + sigmoid
  k_pool2<<<1024, B256, 0, stream>>>(out2, bat, pool, N);
  k_final<<<cdiv(NG * DOUT, B256), B256, 0, stream>>>(pool, cnt, b2, out);
}

// Round 6
// 312.763 us; speedup vs baseline: 4.4372x; 1.1123x over previous
//
#include <hip/hip_runtime.h>
#include <hip/hip_bf16.h>
#include <math.h>

static constexpr int NG   = 64;   // graphs
static constexpr int DIN  = 128;
static constexpr int DHID = 128;
static constexpr int DOUT = 64;
static constexpr int SCAN_CH = 1024;  // elements per scan block (256 thr x 4)

typedef short bf16x8 __attribute__((ext_vector_type(8)));
typedef float f32x4  __attribute__((ext_vector_type(4)));

__device__ __forceinline__ float bf2f(unsigned short u) {
  unsigned int x = ((unsigned int)u) << 16;
  return __builtin_bit_cast(float, x);
}
__device__ __forceinline__ unsigned short f2bf(float f) {  // round-to-nearest-even
  unsigned int x = __builtin_bit_cast(unsigned int, f);
  unsigned int r = x + 0x7fffu + ((x >> 16) & 1u);
  return (unsigned short)(r >> 16);
}
__device__ __forceinline__ bf16x8 pack8(float4 a, float4 b) {
  bf16x8 r;
  r[0] = (short)f2bf(a.x); r[1] = (short)f2bf(a.y);
  r[2] = (short)f2bf(a.z); r[3] = (short)f2bf(a.w);
  r[4] = (short)f2bf(b.x); r[5] = (short)f2bf(b.y);
  r[6] = (short)f2bf(b.z); r[7] = (short)f2bf(b.w);
  return r;
}

// ---------------- small utility kernels ----------------

__global__ void k_zero(float* __restrict__ p, int n) {
  int i = blockIdx.x * blockDim.x + threadIdx.x;
  if (i < n) p[i] = 0.0f;
}

__global__ void k_degi(const int* __restrict__ dst, int* __restrict__ degc, int E) {
  int i = blockIdx.x * blockDim.x + threadIdx.x;
  if (i < E) atomicAdd(&degc[dst[i]], 1);
}

// batch is sorted -> per-graph node count via binary search (no atomics)
__global__ void k_cnt_bs(const int* __restrict__ batch, float* __restrict__ cnt, int N) {
  int g = threadIdx.x;
  if (g >= NG) return;
  auto lower_bound = [&](int key) {
    int lo = 0, hi = N;
    while (lo < hi) {
      int mid = (lo + hi) >> 1;
      if (batch[mid] < key) lo = mid + 1; else hi = mid;
    }
    return lo;
  };
  cnt[g] = (float)(lower_bound(g + 1) - lower_bound(g));
}

__global__ void k_dinv(const int* __restrict__ degc, float* __restrict__ dinv, int N) {
  int i = blockIdx.x * blockDim.x + threadIdx.x;
  if (i < N) dinv[i] = rsqrtf((float)degc[i] + 1.0f);  // +1 self-loop
}

// W [K][NC] fp32 -> Wt [NC][K] bf16 (tiny, L2-resident)
__global__ void k_wt(const float* __restrict__ W, unsigned short* __restrict__ Wt,
                     int K, int NC) {
  int i = blockIdx.x * blockDim.x + threadIdx.x;
  if (i >= K * NC) return;
  int n = i / K, k = i % K;
  Wt[i] = f2bf(W[(size_t)k * NC + n]);
}

// ---------------- exclusive prefix scan over degc -> rowptr (3 kernels) ----------------

__global__ void k_scanA(const int* __restrict__ in, int* __restrict__ bsum, int n) {
  __shared__ int s[256];
  int base = blockIdx.x * SCAN_CH;
  int t = threadIdx.x;
  int sum = 0;
#pragma unroll
  for (int k = 0; k < 4; ++k) {
    int i = base + t * 4 + k;
    if (i < n) sum += in[i];
  }
  s[t] = sum; __syncthreads();
  for (int off = 128; off > 0; off >>= 1) {
    if (t < off) s[t] += s[t + off];
    __syncthreads();
  }
  if (t == 0) bsum[blockIdx.x] = s[0];
}

__global__ void k_scanB(const int* __restrict__ bsum, int* __restrict__ boff, int nb) {
  __shared__ int s[128];
  int t = threadIdx.x;  // 128 threads, nb <= 128
  int mine = (t < nb) ? bsum[t] : 0;
  s[t] = mine; __syncthreads();
  for (int off = 1; off < 128; off <<= 1) {
    int v = (t >= off) ? s[t - off] : 0;
    __syncthreads();
    s[t] += v;
    __syncthreads();
  }
  if (t < nb) boff[t] = s[t] - mine;  // exclusive
}

__global__ void k_scanC(const int* __restrict__ in, const int* __restrict__ boff,
                        int* __restrict__ rowptr, int* __restrict__ cursor, int n, int E) {
  __shared__ int s[256];
  int base = blockIdx.x * SCAN_CH;
  int t = threadIdx.x;
  int loc[4];
  int sum = 0;
#pragma unroll
  for (int k = 0; k < 4; ++k) {
    int i = base + t * 4 + k;
    loc[k] = (i < n) ? in[i] : 0;
    sum += loc[k];
  }
  s[t] = sum; __syncthreads();
  for (int off = 1; off < 256; off <<= 1) {
    int v = (t >= off) ? s[t - off] : 0;
    __syncthreads();
    s[t] += v;
    __syncthreads();
  }
  int run = s[t] - sum + boff[blockIdx.x];  // exclusive across grid
#pragma unroll
  for (int k = 0; k < 4; ++k) {
    int i = base + t * 4 + k;
    if (i < n) { rowptr[i] = run; cursor[i] = run; run += loc[k]; }
  }
  if (blockIdx.x == 0 && t == 0) rowptr[n] = E;
}

// slot-fill: col[pos] = src
__global__ void k_fill(const int* __restrict__ src, const int* __restrict__ dst,
                       int* __restrict__ cursor, int* __restrict__ col, int E) {
  int i = blockIdx.x * blockDim.x + threadIdx.x;
  if (i < E) {
    int pos = atomicAdd(&cursor[dst[i]], 1);
    col[pos] = src[i];
  }
}

// ---------------- MFMA bf16 GEMM: Cbf[r][n] = bf16( dinv[r] * (A@W)[r][n] ) -------------
// Swapped operands: D = mfma(Wt_frag, x_frag) -> D[n][m]; Wt [NC][K] bf16 staged in
// XOR-swizzled LDS (conflict-free ds_read_b128); x rows read k-contiguous from global fp32.
// FUSE_IN: A element -> relu(a + bias[k]) before bf16 conversion.
template<int NC, bool FUSE_IN>
__launch_bounds__(256)
__global__ void k_gemm_mfma(const float* __restrict__ A, const unsigned short* __restrict__ Wt,
                            unsigned short* __restrict__ Cbf, const float* __restrict__ bias,
                            const float* __restrict__ dinv, int M) {
  constexpr int K  = 128;
  constexpr int NT = NC / 16;              // n-tiles per wave
  __shared__ unsigned short Wlds[NC * K];  // swizzled: byte = n*256 + (kb ^ ((n&7)<<4))
  const int tid = threadIdx.x;
  for (int c = tid; c < NC * K / 4; c += 256) {
    ushort4 v = *reinterpret_cast<const ushort4*>(Wt + c * 4);
    int n  = (c * 4) / K;
    int kb = ((c * 4) % K) * 2;
    *reinterpret_cast<ushort4*>((char*)Wlds + n * (K * 2) + (kb ^ ((n & 7) << 4))) = v;
  }
  __syncthreads();

  const int lane  = tid & 63;
  const int w     = tid >> 6;
  const int khalf = lane >> 4;             // 0..3
  const int r     = blockIdx.x * 64 + w * 16 + (lane & 15);
  const int rl    = min(r, M - 1);

  // x fragments: 16 rows x K, 8 contiguous k per lane per frag
  bf16x8 xf[K / 32];
  const float* Ar = A + (size_t)rl * K;
#pragma unroll
  for (int kk = 0; kk < K / 32; ++kk) {
    int kb = kk * 32 + khalf * 8;
    float4 v0 = *reinterpret_cast<const float4*>(Ar + kb);
    float4 v1 = *reinterpret_cast<const float4*>(Ar + kb + 4);
    if (FUSE_IN) {
      float4 b0 = *reinterpret_cast<const float4*>(bias + kb);
      float4 b1 = *reinterpret_cast<const float4*>(bias + kb + 4);
      v0.x = fmaxf(v0.x + b0.x, 0.f); v0.y = fmaxf(v0.y + b0.y, 0.f);
      v0.z = fmaxf(v0.z + b0.z, 0.f); v0.w = fmaxf(v0.w + b0.w, 0.f);
      v1.x = fmaxf(v1.x + b1.x, 0.f); v1.y = fmaxf(v1.y + b1.y, 0.f);
      v1.z = fmaxf(v1.z + b1.z, 0.f); v1.w = fmaxf(v1.w + b1.w, 0.f);
    }
    xf[kk] = pack8(v0, v1);
  }

  f32x4 acc[NT] = {};
#pragma unroll
  for (int nt = 0; nt < NT; ++nt) {
    const int n = nt * 16 + (lane & 15);
    const char* wrow = (const char*)Wlds + n * (K * 2);
    const int sw = (n & 7) << 4;
#pragma unroll
    for (int kk = 0; kk < K / 32; ++kk) {
      int kb = (kk * 32 + khalf * 8) * 2;
      bf16x8 wf = *reinterpret_cast<const bf16x8*>(wrow + (kb ^ sw));
      acc[nt] = __builtin_amdgcn_mfma_f32_16x16x32_bf16(wf, xf[kk], acc[nt], 0, 0, 0);
    }
  }

  if (r < M) {
    float dv = dinv[r];
    unsigned short* Crow = Cbf + (size_t)r * NC;
#pragma unroll
    for (int nt = 0; nt < NT; ++nt) {
      ushort4 o;
      o.x = f2bf(acc[nt][0] * dv); o.y = f2bf(acc[nt][1] * dv);
      o.z = f2bf(acc[nt][2] * dv); o.w = f2bf(acc[nt][3] * dv);
      *reinterpret_cast<ushort4*>(Crow + nt * 16 + khalf * 4) = o;
    }
  }
}

// ---------------- CSR gather over pre-scaled bf16 rows ----------------
// out[v] = dinv[v] * ( hbf[v] + sum_{e} hbf[col[e]] )   (fp32 accumulate)
template<int D>
__global__ void k_gather_bf(const int* __restrict__ rowptr, const int* __restrict__ col,
                            const float* __restrict__ dinv,
                            const unsigned short* __restrict__ hbf,
                            float* __restrict__ outp, int N) {
  constexpr int LPR = D / 2;       // lanes per row (ushort2 each)
  constexpr int RPW = 64 / LPR;    // rows per wave step (1 or 2)
  int wid  = (blockIdx.x * blockDim.x + threadIdx.x) >> 6;
  int lane = threadIdx.x & 63;
  if (wid >= N) return;
  const int v   = wid;
  const int sub = lane / LPR;
  const int li  = lane % LPR;
  const size_t eoff = 2 * li;
  int beg = rowptr[v], end = rowptr[v + 1];
  float a0 = 0.f, a1 = 0.f;
  if (sub == 0) {  // self term once
    ushort2 u = *reinterpret_cast<const ushort2*>(hbf + (size_t)v * D + eoff);
    a0 = bf2f(u.x); a1 = bf2f(u.y);
  }
  int j = beg + sub;
  for (; j + 3 * RPW < end; j += 4 * RPW) {
    int s0 = col[j], s1 = col[j + RPW], s2 = col[j + 2 * RPW], s3 = col[j + 3 * RPW];
    ushort2 u0 = *reinterpret_cast<const ushort2*>(hbf + (size_t)s0 * D + eoff);
    ushort2 u1 = *reinterpret_cast<const ushort2*>(hbf + (size_t)s1 * D + eoff);
    ushort2 u2 = *reinterpret_cast<const ushort2*>(hbf + (size_t)s2 * D + eoff);
    ushort2 u3 = *reinterpret_cast<const ushort2*>(hbf + (size_t)s3 * D + eoff);
    a0 += (bf2f(u0.x) + bf2f(u1.x)) + (bf2f(u2.x) + bf2f(u3.x));
    a1 += (bf2f(u0.y) + bf2f(u1.y)) + (bf2f(u2.y) + bf2f(u3.y));
  }
  for (; j < end; j += RPW) {
    int s = col[j];
    ushort2 u = *reinterpret_cast<const ushort2*>(hbf + (size_t)s * D + eoff);
    a0 += bf2f(u.x); a1 += bf2f(u.y);
  }
  if constexpr (RPW == 2) {
    a0 += __shfl_xor(a0, 32, 64);
    a1 += __shfl_xor(a1, 32, 64);
  }
  if (sub == 0) {
    float dv = dinv[v];
    *reinterpret_cast<float2*>(outp + (size_t)v * D + eoff) = make_float2(dv * a0, dv * a1);
  }
}

// ---------------- graph mean-pool: batch sorted -> segmented column sum ----------------
__global__ void k_pool2(const float* __restrict__ out2, const int* __restrict__ batch,
                        float* __restrict__ pool, int N) {
  int wid  = (blockIdx.x * blockDim.x + threadIdx.x) >> 6;
  int lane = threadIdx.x & 63;
  int nw   = (gridDim.x * blockDim.x) >> 6;
  int per  = (N + nw - 1) / nw;
  int n0 = wid * per, n1 = min(n0 + per, N);
  if (n0 >= n1) return;
  int g = batch[n0];
  float acc = 0.f;
  int n = n0;
  while (n < n1) {
    if (n + 4 <= n1 && batch[n + 3] == g) {
      float a0 = out2[(size_t)(n + 0) * DOUT + lane];
      float a1 = out2[(size_t)(n + 1) * DOUT + lane];
      float a2 = out2[(size_t)(n + 2) * DOUT + lane];
      float a3 = out2[(size_t)(n + 3) * DOUT + lane];
      acc += (a0 + a1) + (a2 + a3);
      n += 4;
    } else {
      int bg = batch[n];
      if (bg != g) { atomicAdd(&pool[g * DOUT + lane], acc); acc = 0.f; g = bg; }
      acc += out2[(size_t)n * DOUT + lane];
      ++n;
    }
  }
  atomicAdd(&pool[g * DOUT + lane], acc);
}

__global__ void k_final(const float* __restrict__ pool, const float* __restrict__ cnt,
                        const float* __restrict__ b2, float* __restrict__ out) {
  int i = blockIdx.x * blockDim.x + threadIdx.x;
  if (i >= NG * DOUT) return;
  int g = i >> 6, c = i & 63;
  float cg = cnt[g];
  float v = (cg > 0.f) ? (pool[i] / cg + b2[c]) : 0.f;
  out[i] = 1.f / (1.f + expf(-v));
}

// ---------------- launcher ----------------
extern "C" void kernel_launch(void* const* d_in, const int* in_sizes, int n_in,
                              void* d_out, int out_size, void* d_ws, size_t ws_size,
                              hipStream_t stream) {
  const float* x    = (const float*)d_in[0];
  const int*   ei   = (const int*)d_in[1];
  const int*   bat  = (const int*)d_in[2];
  const float* W1   = (const float*)d_in[3];
  const float* b1   = (const float*)d_in[4];
  const float* W2   = (const float*)d_in[5];
  const float* b2   = (const float*)d_in[6];
  float* out = (float*)d_out;

  const int N = in_sizes[0] / DIN;   // 100000
  const int E = in_sizes[1] / 2;     // 600000
  const int* src = ei;
  const int* dst = ei + E;

  // workspace layout
  char* wp = (char*)d_ws;
  auto alloc = [&](size_t bytes) { char* r = wp; wp += (bytes + 15) & ~(size_t)15; return r; };
  int*   degc   = (int*)  alloc(sizeof(int) * N);
  int*   rowptr = (int*)  alloc(sizeof(int) * (N + 1));
  int*   cursor = (int*)  alloc(sizeof(int) * (N + 1));
  int*   col    = (int*)  alloc(sizeof(int) * E);
  int*   bsum   = (int*)  alloc(sizeof(int) * 128);
  int*   boff   = (int*)  alloc(sizeof(int) * 128);
  float* dinv   = (float*)alloc(sizeof(float) * N);
  float* cnt    = (float*)alloc(sizeof(float) * NG);
  float* pool   = (float*)alloc(sizeof(float) * NG * DOUT);
  unsigned short* Wt1 = (unsigned short*)alloc(sizeof(unsigned short) * DHID * DIN);
  unsigned short* Wt2 = (unsigned short*)alloc(sizeof(unsigned short) * DOUT * DHID);
  unsigned short* hbf1 = (unsigned short*)alloc(sizeof(unsigned short) * (size_t)N * DHID);
  float* out1   = (float*)alloc(sizeof(float) * (size_t)N * DHID);
  unsigned short* hbf2 = hbf1;               // hbf1 dead after gather1
  float* out2   = out1;                      // out1 dead after gemm2

  const int B256 = 256;
  auto cdiv = [](int a, int b) { return (a + b - 1) / b; };
  const int nScanB = cdiv(N, SCAN_CH);       // 98 <= 128

  // 1) zero degc and pool
  k_zero<<<cdiv(N, B256), B256, 0, stream>>>((float*)degc, N);
  k_zero<<<cdiv(NG * DOUT, B256), B256, 0, stream>>>(pool, NG * DOUT);

  // 2) CSR build + cnt + dinv + W transposes
  k_degi<<<cdiv(E, B256), B256, 0, stream>>>(dst, degc, E);
  k_cnt_bs<<<1, 128, 0, stream>>>(bat, cnt, N);
  k_wt<<<cdiv(DHID * DIN, B256), B256, 0, stream>>>(W1, Wt1, DIN, DHID);
  k_wt<<<cdiv(DOUT * DHID, B256), B256, 0, stream>>>(W2, Wt2, DHID, DOUT);
  k_scanA<<<nScanB, 256, 0, stream>>>(degc, bsum, N);
  k_scanB<<<1, 128, 0, stream>>>(bsum, boff, nScanB);
  k_scanC<<<nScanB, 256, 0, stream>>>(degc, boff, rowptr, cursor, N, E);
  k_fill<<<cdiv(E, B256), B256, 0, stream>>>(src, dst, cursor, col, E);
  k_dinv<<<cdiv(N, B256), B256, 0, stream>>>(degc, dinv, N);

  // 3) hbf1 = bf16( dinv * (x @ W1) )   [MFMA]
  k_gemm_mfma<DHID, false><<<cdiv(N, 64), B256, 0, stream>>>(x, Wt1, hbf1, nullptr, dinv, N);

  // 4) layer-1 propagate: out1 = dinv * (self + neighbor sum)   [fp32]
  k_gather_bf<DHID><<<cdiv(N * 64, B256), B256, 0, stream>>>(rowptr, col, dinv, hbf1, out1, N);

  // 5) hbf2 = bf16( dinv * (relu(out1 + b1) @ W2) )   [MFMA]
  k_gemm_mfma<DOUT, true><<<cdiv(N, 64), B256, 0, stream>>>(out1, Wt2, hbf2, b1, dinv, N);

  // 6) layer-2 propagate
  k_gather_bf<DOUT><<<cdiv(N * 64, B256), B256, 0, stream>>>(rowptr, col, dinv, hbf2, out2, N);

  // 7) graph mean pool + bias + sigmoid
  k_pool2<<<1024, B256, 0, stream>>>(out2, bat, pool, N);
  k_final<<<cdiv(NG * DOUT, B256), B256, 0, stream>>>(pool, cnt, b2, out);
}

// Round 7
// 276.657 us; speedup vs baseline: 5.0163x; 1.1305x over previous
//
#include <hip/hip_runtime.h>
#include <hip/hip_bf16.h>
#include <math.h>

static constexpr int NG   = 64;   // graphs
static constexpr int DIN  = 128;
static constexpr int DHID = 128;
static constexpr int DOUT = 64;
static constexpr int SCAN_CH = 1024;  // elements per scan block (256 thr x 4)

typedef short bf16x8 __attribute__((ext_vector_type(8)));
typedef float f32x4  __attribute__((ext_vector_type(4)));

__device__ __forceinline__ float bf2f(unsigned short u) {
  unsigned int x = ((unsigned int)u) << 16;
  return __builtin_bit_cast(float, x);
}
__device__ __forceinline__ unsigned short f2bf(float f) {  // round-to-nearest-even
  unsigned int x = __builtin_bit_cast(unsigned int, f);
  unsigned int r = x + 0x7fffu + ((x >> 16) & 1u);
  return (unsigned short)(r >> 16);
}
__device__ __forceinline__ bf16x8 pack8(float4 a, float4 b) {
  bf16x8 r;
  r[0] = (short)f2bf(a.x); r[1] = (short)f2bf(a.y);
  r[2] = (short)f2bf(a.z); r[3] = (short)f2bf(a.w);
  r[4] = (short)f2bf(b.x); r[5] = (short)f2bf(b.y);
  r[6] = (short)f2bf(b.z); r[7] = (short)f2bf(b.w);
  return r;
}

// ---------------- small utility kernels ----------------

__global__ void k_zero2(int* __restrict__ p1, int n1, float* __restrict__ p2, int n2) {
  int i = blockIdx.x * blockDim.x + threadIdx.x;
  if (i < n1) p1[i] = 0;
  else if (i < n1 + n2) p2[i - n1] = 0.f;
}

__global__ void k_degi(const int* __restrict__ dst, int* __restrict__ degc, int E) {
  int i = blockIdx.x * blockDim.x + threadIdx.x;
  if (i < E) atomicAdd(&degc[dst[i]], 1);
}

// merged: Wt1 = bf16(W1^T), Wt2 = bf16(W2^T), cnt via binary search on sorted batch
__global__ void k_misc(const float* __restrict__ W1, unsigned short* __restrict__ Wt1,
                       const float* __restrict__ W2, unsigned short* __restrict__ Wt2,
                       const int* __restrict__ batch, float* __restrict__ cnt, int N) {
  int i = blockIdx.x * blockDim.x + threadIdx.x;
  if (i < DHID * DIN) {                       // Wt1 [DHID][DIN]
    int n = i / DIN, k = i % DIN;
    Wt1[i] = f2bf(W1[(size_t)k * DHID + n]);
  } else if (i < DHID * DIN + DOUT * DHID) {  // Wt2 [DOUT][DHID]
    int j = i - DHID * DIN;
    int n = j / DHID, k = j % DHID;
    Wt2[j] = f2bf(W2[(size_t)k * DOUT + n]);
  } else if (i < DHID * DIN + DOUT * DHID + NG) {
    int g = i - DHID * DIN - DOUT * DHID;
    auto lower_bound = [&](int key) {
      int lo = 0, hi = N;
      while (lo < hi) {
        int mid = (lo + hi) >> 1;
        if (batch[mid] < key) lo = mid + 1; else hi = mid;
      }
      return lo;
    };
    cnt[g] = (float)(lower_bound(g + 1) - lower_bound(g));
  }
}

// ---------------- exclusive prefix scan over degc -> rowptr (3 kernels) ----------------

__global__ void k_scanA(const int* __restrict__ in, int* __restrict__ bsum, int n) {
  __shared__ int s[256];
  int base = blockIdx.x * SCAN_CH;
  int t = threadIdx.x;
  int sum = 0;
#pragma unroll
  for (int k = 0; k < 4; ++k) {
    int i = base + t * 4 + k;
    if (i < n) sum += in[i];
  }
  s[t] = sum; __syncthreads();
  for (int off = 128; off > 0; off >>= 1) {
    if (t < off) s[t] += s[t + off];
    __syncthreads();
  }
  if (t == 0) bsum[blockIdx.x] = s[0];
}

__global__ void k_scanB(const int* __restrict__ bsum, int* __restrict__ boff, int nb) {
  __shared__ int s[128];
  int t = threadIdx.x;  // 128 threads, nb <= 128
  int mine = (t < nb) ? bsum[t] : 0;
  s[t] = mine; __syncthreads();
  for (int off = 1; off < 128; off <<= 1) {
    int v = (t >= off) ? s[t - off] : 0;
    __syncthreads();
    s[t] += v;
    __syncthreads();
  }
  if (t < nb) boff[t] = s[t] - mine;  // exclusive
}

// scanC + dinv fused (saves a kernel + an extra pass over degc)
__global__ void k_scanC(const int* __restrict__ in, const int* __restrict__ boff,
                        int* __restrict__ rowptr, int* __restrict__ cursor,
                        float* __restrict__ dinv, int n, int E) {
  __shared__ int s[256];
  int base = blockIdx.x * SCAN_CH;
  int t = threadIdx.x;
  int loc[4];
  int sum = 0;
#pragma unroll
  for (int k = 0; k < 4; ++k) {
    int i = base + t * 4 + k;
    loc[k] = (i < n) ? in[i] : 0;
    sum += loc[k];
  }
  s[t] = sum; __syncthreads();
  for (int off = 1; off < 256; off <<= 1) {
    int v = (t >= off) ? s[t - off] : 0;
    __syncthreads();
    s[t] += v;
    __syncthreads();
  }
  int run = s[t] - sum + boff[blockIdx.x];  // exclusive across grid
#pragma unroll
  for (int k = 0; k < 4; ++k) {
    int i = base + t * 4 + k;
    if (i < n) {
      rowptr[i] = run; cursor[i] = run; run += loc[k];
      dinv[i] = rsqrtf((float)loc[k] + 1.0f);  // +1 self-loop
    }
  }
  if (blockIdx.x == 0 && t == 0) rowptr[n] = E;
}

// slot-fill: col[pos] = src
__global__ void k_fill(const int* __restrict__ src, const int* __restrict__ dst,
                       int* __restrict__ cursor, int* __restrict__ col, int E) {
  int i = blockIdx.x * blockDim.x + threadIdx.x;
  if (i < E) {
    int pos = atomicAdd(&cursor[dst[i]], 1);
    col[pos] = src[i];
  }
}

// ---------------- MFMA bf16 GEMM: Cbf[r][n] = bf16( dinv[r] * (A@W)[r][n] ) -------------
// Swapped operands: D = mfma(Wt_frag, x_frag) -> D[n][m]; Wt [NC][128] bf16 staged in
// XOR-swizzled LDS (conflict-free ds_read_b128). A is fp32 (ABF16=false) or bf16 rows.
template<int NC, bool ABF16>
__launch_bounds__(256)
__global__ void k_gemm_mfma(const void* __restrict__ Av, const unsigned short* __restrict__ Wt,
                            unsigned short* __restrict__ Cbf,
                            const float* __restrict__ dinv, int M) {
  constexpr int K  = 128;
  constexpr int NT = NC / 16;              // n-tiles per wave
  __shared__ unsigned short Wlds[NC * K];  // swizzled: byte = n*256 + (kb ^ ((n&7)<<4))
  const int tid = threadIdx.x;
  for (int c = tid; c < NC * K / 4; c += 256) {
    ushort4 v = *reinterpret_cast<const ushort4*>(Wt + c * 4);
    int n  = (c * 4) / K;
    int kb = ((c * 4) % K) * 2;
    *reinterpret_cast<ushort4*>((char*)Wlds + n * (K * 2) + (kb ^ ((n & 7) << 4))) = v;
  }
  __syncthreads();

  const int lane  = tid & 63;
  const int w     = tid >> 6;
  const int khalf = lane >> 4;             // 0..3
  const int r     = blockIdx.x * 64 + w * 16 + (lane & 15);
  const int rl    = min(r, M - 1);

  // x fragments: 8 contiguous k per lane per frag
  bf16x8 xf[K / 32];
  if constexpr (ABF16) {
    const unsigned short* Ar = (const unsigned short*)Av + (size_t)rl * K;
#pragma unroll
    for (int kk = 0; kk < K / 32; ++kk)
      xf[kk] = *reinterpret_cast<const bf16x8*>(Ar + kk * 32 + khalf * 8);
  } else {
    const float* Ar = (const float*)Av + (size_t)rl * K;
#pragma unroll
    for (int kk = 0; kk < K / 32; ++kk) {
      int kb = kk * 32 + khalf * 8;
      float4 v0 = *reinterpret_cast<const float4*>(Ar + kb);
      float4 v1 = *reinterpret_cast<const float4*>(Ar + kb + 4);
      xf[kk] = pack8(v0, v1);
    }
  }

  f32x4 acc[NT] = {};
#pragma unroll
  for (int nt = 0; nt < NT; ++nt) {
    const int n = nt * 16 + (lane & 15);
    const char* wrow = (const char*)Wlds + n * (K * 2);
    const int sw = (n & 7) << 4;
#pragma unroll
    for (int kk = 0; kk < K / 32; ++kk) {
      int kb = (kk * 32 + khalf * 8) * 2;
      bf16x8 wf = *reinterpret_cast<const bf16x8*>(wrow + (kb ^ sw));
      acc[nt] = __builtin_amdgcn_mfma_f32_16x16x32_bf16(wf, xf[kk], acc[nt], 0, 0, 0);
    }
  }

  if (r < M) {
    float dv = dinv[r];
    unsigned short* Crow = Cbf + (size_t)r * NC;
#pragma unroll
    for (int nt = 0; nt < NT; ++nt) {
      ushort4 o;
      o.x = f2bf(acc[nt][0] * dv); o.y = f2bf(acc[nt][1] * dv);
      o.z = f2bf(acc[nt][2] * dv); o.w = f2bf(acc[nt][3] * dv);
      *reinterpret_cast<ushort4*>(Crow + nt * 16 + khalf * 4) = o;
    }
  }
}

// ---------------- CSR gather over pre-scaled bf16 rows, fused epilogue ----------------
// acc = hbf[v] + sum_e hbf[col[e]]  (fp32)
// RELU_BIAS: out = bf16(relu(dinv[v]*acc + bias[f]))  else out = bf16(dinv[v]*acc)
// ushort4/lane -> D/4 lanes per row -> 64*4/D nodes per wave (2 for D=128, 4 for D=64)
template<int D, bool RELU_BIAS>
__global__ void k_gather_fuse(const int* __restrict__ rowptr, const int* __restrict__ col,
                              const float* __restrict__ dinv,
                              const unsigned short* __restrict__ hbf,
                              unsigned short* __restrict__ outbf,
                              const float* __restrict__ bias, int N) {
  constexpr int LPR = D / 4;       // lanes per row (ushort4 each)
  constexpr int NPW = 64 / LPR;    // nodes per wave
  int wid  = (blockIdx.x * blockDim.x + threadIdx.x) >> 6;
  int lane = threadIdx.x & 63;
  int sub  = lane / LPR;
  int li   = lane % LPR;
  int v = wid * NPW + sub;
  if (v >= N) return;
  const size_t eoff = 4 * (size_t)li;
  int beg = rowptr[v], end = rowptr[v + 1];
  ushort4 u = *reinterpret_cast<const ushort4*>(hbf + (size_t)v * D + eoff);  // self
  float a0 = bf2f(u.x), a1 = bf2f(u.y), a2 = bf2f(u.z), a3 = bf2f(u.w);
  int j = beg;
  for (; j + 3 < end; j += 4) {  // 4 independent row loads in flight
    int s0 = col[j], s1 = col[j + 1], s2 = col[j + 2], s3 = col[j + 3];
    ushort4 u0 = *reinterpret_cast<const ushort4*>(hbf + (size_t)s0 * D + eoff);
    ushort4 u1 = *reinterpret_cast<const ushort4*>(hbf + (size_t)s1 * D + eoff);
    ushort4 u2 = *reinterpret_cast<const ushort4*>(hbf + (size_t)s2 * D + eoff);
    ushort4 u3 = *reinterpret_cast<const ushort4*>(hbf + (size_t)s3 * D + eoff);
    a0 += (bf2f(u0.x) + bf2f(u1.x)) + (bf2f(u2.x) + bf2f(u3.x));
    a1 += (bf2f(u0.y) + bf2f(u1.y)) + (bf2f(u2.y) + bf2f(u3.y));
    a2 += (bf2f(u0.z) + bf2f(u1.z)) + (bf2f(u2.z) + bf2f(u3.z));
    a3 += (bf2f(u0.w) + bf2f(u1.w)) + (bf2f(u2.w) + bf2f(u3.w));
  }
  for (; j < end; ++j) {
    int s = col[j];
    ushort4 uu = *reinterpret_cast<const ushort4*>(hbf + (size_t)s * D + eoff);
    a0 += bf2f(uu.x); a1 += bf2f(uu.y); a2 += bf2f(uu.z); a3 += bf2f(uu.w);
  }
  float dv = dinv[v];
  a0 *= dv; a1 *= dv; a2 *= dv; a3 *= dv;
  if (RELU_BIAS) {
    float4 b = *reinterpret_cast<const float4*>(bias + eoff);
    a0 = fmaxf(a0 + b.x, 0.f); a1 = fmaxf(a1 + b.y, 0.f);
    a2 = fmaxf(a2 + b.z, 0.f); a3 = fmaxf(a3 + b.w, 0.f);
  }
  ushort4 o = make_ushort4(f2bf(a0), f2bf(a1), f2bf(a2), f2bf(a3));
  *reinterpret_cast<ushort4*>(outbf + (size_t)v * D + eoff) = o;
}

// ---------------- graph mean-pool over bf16 rows (batch sorted) ----------------
__global__ void k_pool2(const unsigned short* __restrict__ out2, const int* __restrict__ batch,
                        float* __restrict__ pool, int N) {
  int wid  = (blockIdx.x * blockDim.x + threadIdx.x) >> 6;
  int lane = threadIdx.x & 63;
  int nw   = (gridDim.x * blockDim.x) >> 6;
  int per  = (N + nw - 1) / nw;
  int n0 = wid * per, n1 = min(n0 + per, N);
  if (n0 >= n1) return;
  int g = batch[n0];
  float acc = 0.f;
  int n = n0;
  while (n < n1) {
    if (n + 4 <= n1 && batch[n + 3] == g) {
      float a0 = bf2f(out2[(size_t)(n + 0) * DOUT + lane]);
      float a1 = bf2f(out2[(size_t)(n + 1) * DOUT + lane]);
      float a2 = bf2f(out2[(size_t)(n + 2) * DOUT + lane]);
      float a3 = bf2f(out2[(size_t)(n + 3) * DOUT + lane]);
      acc += (a0 + a1) + (a2 + a3);
      n += 4;
    } else {
      int bg = batch[n];
      if (bg != g) { atomicAdd(&pool[g * DOUT + lane], acc); acc = 0.f; g = bg; }
      acc += bf2f(out2[(size_t)n * DOUT + lane]);
      ++n;
    }
  }
  atomicAdd(&pool[g * DOUT + lane], acc);
}

__global__ void k_final(const float* __restrict__ pool, const float* __restrict__ cnt,
                        const float* __restrict__ b2, float* __restrict__ out) {
  int i = blockIdx.x * blockDim.x + threadIdx.x;
  if (i >= NG * DOUT) return;
  int g = i >> 6, c = i & 63;
  float cg = cnt[g];
  float v = (cg > 0.f) ? (pool[i] / cg + b2[c]) : 0.f;
  out[i] = 1.f / (1.f + expf(-v));
}

// ---------------- launcher ----------------
extern "C" void kernel_launch(void* const* d_in, const int* in_sizes, int n_in,
                              void* d_out, int out_size, void* d_ws, size_t ws_size,
                              hipStream_t stream) {
  const float* x    = (const float*)d_in[0];
  const int*   ei   = (const int*)d_in[1];
  const int*   bat  = (const int*)d_in[2];
  const float* W1   = (const float*)d_in[3];
  const float* b1   = (const float*)d_in[4];
  const float* W2   = (const float*)d_in[5];
  const float* b2   = (const float*)d_in[6];
  float* out = (float*)d_out;

  const int N = in_sizes[0] / DIN;   // 100000
  const int E = in_sizes[1] / 2;     // 600000
  const int* src = ei;
  const int* dst = ei + E;

  // workspace layout
  char* wp = (char*)d_ws;
  auto alloc = [&](size_t bytes) { char* r = wp; wp += (bytes + 15) & ~(size_t)15; return r; };
  int*   degc   = (int*)  alloc(sizeof(int) * N);
  int*   rowptr = (int*)  alloc(sizeof(int) * (N + 1));
  int*   cursor = (int*)  alloc(sizeof(int) * (N + 1));
  int*   col    = (int*)  alloc(sizeof(int) * E);
  int*   bsum   = (int*)  alloc(sizeof(int) * 128);
  int*   boff   = (int*)  alloc(sizeof(int) * 128);
  float* dinv   = (float*)alloc(sizeof(float) * N);
  float* cnt    = (float*)alloc(sizeof(float) * NG);
  float* pool   = (float*)alloc(sizeof(float) * NG * DOUT);
  unsigned short* Wt1 = (unsigned short*)alloc(sizeof(unsigned short) * DHID * DIN);
  unsigned short* Wt2 = (unsigned short*)alloc(sizeof(unsigned short) * DOUT * DHID);
  unsigned short* hbf1   = (unsigned short*)alloc(sizeof(unsigned short) * (size_t)N * DHID);
  unsigned short* out1bf = (unsigned short*)alloc(sizeof(unsigned short) * (size_t)N * DHID);
  unsigned short* hbf2   = hbf1;    // hbf1 dead after gather1
  unsigned short* out2bf = out1bf;  // out1bf dead after gemm2

  const int B256 = 256;
  auto cdiv = [](int a, int b) { return (a + b - 1) / b; };
  const int nScanB = cdiv(N, SCAN_CH);       // 98 <= 128

  // 1) zero degc + pool (one launch)
  k_zero2<<<cdiv(N + NG * DOUT, B256), B256, 0, stream>>>(degc, N, pool, NG * DOUT);

  // 2) CSR build + weights transpose + cnt
  k_degi<<<cdiv(E, B256), B256, 0, stream>>>(dst, degc, E);
  k_misc<<<cdiv(DHID * DIN + DOUT * DHID + NG, B256), B256, 0, stream>>>(
      W1, Wt1, W2, Wt2, bat, cnt, N);
  k_scanA<<<nScanB, 256, 0, stream>>>(degc, bsum, N);
  k_scanB<<<1, 128, 0, stream>>>(bsum, boff, nScanB);
  k_scanC<<<nScanB, 256, 0, stream>>>(degc, boff, rowptr, cursor, dinv, N, E);
  k_fill<<<cdiv(E, B256), B256, 0, stream>>>(src, dst, cursor, col, E);

  // 3) hbf1 = bf16( dinv * (x @ W1) )   [MFMA, fp32 A]
  k_gemm_mfma<DHID, false><<<cdiv(N, 64), B256, 0, stream>>>(x, Wt1, hbf1, dinv, N);

  // 4) layer-1 propagate + relu + b1 -> bf16 (2 nodes/wave)
  k_gather_fuse<DHID, true><<<cdiv(cdiv(N, 2) * 64, B256), B256, 0, stream>>>(
      rowptr, col, dinv, hbf1, out1bf, b1, N);

  // 5) hbf2 = bf16( dinv * (out1bf @ W2) )   [MFMA, bf16 A]
  k_gemm_mfma<DOUT, true><<<cdiv(N, 64), B256, 0, stream>>>(out1bf, Wt2, hbf2, dinv, N);

  // 6) layer-2 propagate -> bf16 (4 nodes/wave)
  k_gather_fuse<DOUT, false><<<cdiv(cdiv(N, 4) * 64, B256), B256, 0, stream>>>(
      rowptr, col, dinv, hbf2, out2bf, nullptr, N);

  // 7) graph mean pool + bias + sigmoid
  k_pool2<<<1024, B256, 0, stream>>>(out2bf, bat, pool, N);
  k_final<<<cdiv(NG * DOUT, B256), B256, 0, stream>>>(pool, cnt, b2, out);
}